// Round 8
// baseline (163572.888 us; speedup 1.0000x reference)
//
#include <hip/hip_runtime.h>

#define BATCH 16384
#define LOOK 30
#define HID 1024
#define DEPTH 10
#define NSTEPS 16
#define ALPHA 0.3f

typedef short bf16x8 __attribute__((ext_vector_type(8)));
typedef float f32x4 __attribute__((ext_vector_type(4)));

__device__ __forceinline__ float leaky(float x) { return x > 0.f ? x : ALPHA * x; }

__device__ __forceinline__ unsigned short f2bf(float x) {
  unsigned u = __builtin_bit_cast(unsigned, x);
  unsigned r = u + 0x7FFFu + ((u >> 16) & 1u);
  return (unsigned short)(r >> 16);
}
__device__ __forceinline__ float bf2f(unsigned short b) {
  return __builtin_bit_cast(float, (unsigned)b << 16);
}

#define GLD_LDS16(g, l)                                        \
  __builtin_amdgcn_global_load_lds(                            \
      (const __attribute__((address_space(1))) void*)(g),      \
      (__attribute__((address_space(3))) void*)(l), 16, 0, 0)

// ---------------------------------------------------------------------------
// Prep: W2[k][n] -> W2T[n][k] hi/lo bf16. grid (16,16), 256 thr.
// ---------------------------------------------------------------------------
__global__ __launch_bounds__(256) void k_w2split(const float* __restrict__ W2d,
                                                 short* __restrict__ W2Th,
                                                 short* __restrict__ W2Tl) {
  __shared__ float t[64][65];
  const int kb = blockIdx.x * 64;
  const int nb = blockIdx.y * 64;
  for (int i = threadIdx.x; i < 4096; i += 256) {
    int r = i >> 6, c = i & 63;
    t[r][c] = W2d[(size_t)(kb + r) * HID + nb + c];
  }
  __syncthreads();
  for (int i = threadIdx.x; i < 4096; i += 256) {
    int r = i >> 6, c = i & 63;
    float v = t[c][r];
    unsigned short hi = f2bf(v);
    unsigned short lo = f2bf(v - bf2f(hi));
    W2Th[(size_t)(nb + r) * HID + kb + c] = (short)hi;
    W2Tl[(size_t)(nb + r) * HID + kb + c] = (short)lo;
  }
}

// Prep: W1[30][1024] -> W1T[1024 n][32 k] hi/lo (k 30,31 zero). grid 128.
__global__ __launch_bounds__(256) void k_w1t(const float* __restrict__ W1d,
                                             short* __restrict__ W1Th,
                                             short* __restrict__ W1Tl) {
  const int idx = blockIdx.x * 256 + threadIdx.x;
  if (idx >= 1024 * 32) return;
  const int n = idx >> 5, k = idx & 31;
  float v = (k < LOOK) ? W1d[(size_t)k * HID + n] : 0.f;
  unsigned short hi = f2bf(v);
  unsigned short lo = f2bf(v - bf2f(hi));
  W1Th[idx] = (short)hi;
  W1Tl[idx] = (short)lo;
}

// Prep: W3[1024][30] -> W3T[32 n][1024 k] hi/lo (n 30,31 zero). grid 128.
__global__ __launch_bounds__(256) void k_w3t(const float* __restrict__ W3d,
                                             short* __restrict__ W3Th,
                                             short* __restrict__ W3Tl) {
  const int idx = blockIdx.x * 256 + threadIdx.x;
  if (idx >= 32 * 1024) return;
  const int n = idx >> 10, k = idx & 1023;
  float v = (n < LOOK) ? W3d[(size_t)k * LOOK + n] : 0.f;
  unsigned short hi = f2bf(v);
  unsigned short lo = f2bf(v - bf2f(hi));
  W3Th[idx] = (short)hi;
  W3Tl[idx] = (short)lo;
}

// Init: z = y0 (padded to 32 cols) hi/lo. grid 2048.
__global__ __launch_bounds__(256) void k_zinit(const float* __restrict__ y0,
                                               short* __restrict__ zh,
                                               short* __restrict__ zl) {
  const int idx = blockIdx.x * 256 + threadIdx.x;
  if (idx >= BATCH * 32) return;
  const int r = idx >> 5, c = idx & 31;
  float v = (c < LOOK) ? y0[(size_t)r * LOOK + c] : 0.f;
  unsigned short hi = f2bf(v);
  unsigned short lo = f2bf(v - bf2f(hi));
  zh[idx] = (short)hi;
  zl[idx] = (short)lo;
}

// ---------------------------------------------------------------------------
// Layer1 (MFMA): H1 = leaky(z @ W1 + b1), single K-tile (K=32). [R4 verbatim]
// ---------------------------------------------------------------------------
__global__ __launch_bounds__(512, 2) void k_l1(
    const short* __restrict__ zh, const short* __restrict__ zl,
    const short* __restrict__ W1Th, const short* __restrict__ W1Tl,
    const float* __restrict__ b1d, short* __restrict__ H1h,
    short* __restrict__ H1l) {
  __shared__ short za[2][128 * 32];
  const int tid = threadIdx.x, lane = tid & 63, wave = tid >> 6;
  const int row0 = blockIdx.x * 128;
  const int n0 = blockIdx.y * 256;
  const int wm = wave >> 2, wn = wave & 3;
  const int r15 = lane & 15;
  const int bk = (lane >> 4) * 8;

  bf16x8 bh[4], bl[4];
#pragma unroll
  for (int nj = 0; nj < 4; ++nj) {
    const size_t bo = (size_t)(n0 + wn * 64 + nj * 16 + r15) * 32 + bk;
    bh[nj] = *(const bf16x8*)&W1Th[bo];
    bl[nj] = *(const bf16x8*)&W1Tl[bo];
  }

  GLD_LDS16((const char*)(zh + (size_t)row0 * 32) + tid * 16, &za[0][tid * 8]);
  GLD_LDS16((const char*)(zl + (size_t)row0 * 32) + tid * 16, &za[1][tid * 8]);
  __syncthreads();

  bf16x8 ah[4], al[4];
#pragma unroll
  for (int mi = 0; mi < 4; ++mi) {
    const int ao = (wm * 64 + mi * 16 + r15) * 32 + bk;
    ah[mi] = *(const bf16x8*)&za[0][ao];
    al[mi] = *(const bf16x8*)&za[1][ao];
  }

  f32x4 acc[4][4];
#pragma unroll
  for (int i = 0; i < 4; ++i)
#pragma unroll
    for (int j = 0; j < 4; ++j) acc[i][j] = (f32x4){0.f, 0.f, 0.f, 0.f};

#pragma unroll
  for (int mi = 0; mi < 4; ++mi)
#pragma unroll
    for (int nj = 0; nj < 4; ++nj) {
      acc[mi][nj] = __builtin_amdgcn_mfma_f32_16x16x32_bf16(ah[mi], bh[nj],
                                                            acc[mi][nj], 0, 0, 0);
      acc[mi][nj] = __builtin_amdgcn_mfma_f32_16x16x32_bf16(ah[mi], bl[nj],
                                                            acc[mi][nj], 0, 0, 0);
      acc[mi][nj] = __builtin_amdgcn_mfma_f32_16x16x32_bf16(al[mi], bh[nj],
                                                            acc[mi][nj], 0, 0, 0);
    }

  const int crow = (lane >> 4) * 4;
#pragma unroll
  for (int nj = 0; nj < 4; ++nj) {
    const int col = n0 + wn * 64 + nj * 16 + r15;
    const float bias = b1d[col];
#pragma unroll
    for (int mi = 0; mi < 4; ++mi) {
      const int rb = row0 + wm * 64 + mi * 16 + crow;
#pragma unroll
      for (int r = 0; r < 4; ++r) {
        float v = leaky(acc[mi][nj][r] + bias);
        unsigned short hi = f2bf(v);
        unsigned short lo = f2bf(v - bf2f(hi));
        const size_t o = (size_t)(rb + r) * HID + col;
        H1h[o] = (short)hi;
        H1l[o] = (short)lo;
      }
    }
  }
}

// ---------------------------------------------------------------------------
// Mid (MFMA): H2 = leaky(H1 @ W2 + b2), split-bf16 3-product.
// 256x256 tile, BK=32, 8 waves (2M x 4N), 16x16x32.
// NEW: B (W2T) fragments go global->register (L2-hot, no LDS);
//      A in a 4-slot LDS ring (4 x 32KB), prefetch distance 2,
//      ONE barrier/tile, counted vmcnt(4) gate (never drains in-loop).
// grid 256 blocks (64M x 4N), XCD-chunked swizzle.
// ---------------------------------------------------------------------------
__global__ __launch_bounds__(512, 2) void k_mid(
    const short* __restrict__ H1h, const short* __restrict__ H1l,
    const short* __restrict__ W2Th, const short* __restrict__ W2Tl,
    const float* __restrict__ b2d, short* __restrict__ H2h,
    short* __restrict__ H2l) {
  __shared__ char lds[131072];  // 4 slots x 32KB, A only

  const int tid = threadIdx.x;
  const int lane = tid & 63;
  const int wave = tid >> 6;

  const int bid = blockIdx.x;
  const int wg = (bid & 7) * 32 + (bid >> 3);
  const int mb = wg >> 2, nb = wg & 3;
  const int row0 = mb * 256;
  const int n0 = nb * 256;
  const int wm = wave >> 2;
  const int wnb = wave & 3;
  const int r15 = lane & 15;
  const int kq = lane >> 4;
  const int l7 = lane & 7;
  const int l3 = lane >> 3;

  // ---- A staging: 32 chunks of 1KB (8 rows x 128B [hi64|lo64] swizzled);
  //      wave w loads chunks w*4..w*4+3 (rows w*32..w*32+32), pre-swizzled src.
  const char* srcA[4];
  {
    const int s = l7 ^ l3;  // logical slot fetched into phys slot l7
    const char* base = (s < 4) ? (const char*)H1h : (const char*)H1l;
#pragma unroll
    for (int i = 0; i < 4; ++i) {
      const int c = wave * 4 + i;
      srcA[i] = base + (size_t)(row0 + c * 8 + l3) * 2048 + (size_t)(s & 3) * 16;
    }
  }
  const int dchunk0 = wave * 4096;

  // ---- A fragment read offsets (phys slot = log ^ (row&7); row&7 == l7)
  const int offA0 = (wm * 128 + r15) * 128 + ((0 + kq) ^ l7) * 16;
  const int offA1 = (wm * 128 + r15) * 128 + ((4 + kq) ^ l7) * 16;

  // ---- B column base pointers (register path, shorts)
  const short* bColH[4];
  const short* bColL[4];
#pragma unroll
  for (int nj = 0; nj < 4; ++nj) {
    const int col = n0 + wnb * 64 + nj * 16 + r15;
    bColH[nj] = W2Th + (size_t)col * 1024 + kq * 8;
    bColL[nj] = W2Tl + (size_t)col * 1024 + kq * 8;
  }

  f32x4 acc[8][4];
#pragma unroll
  for (int i = 0; i < 8; ++i)
#pragma unroll
    for (int j = 0; j < 4; ++j) acc[i][j] = (f32x4){0.f, 0.f, 0.f, 0.f};

#define ISSUE_A(t_)                                                        \
  {                                                                        \
    _Pragma("unroll") for (int i_ = 0; i_ < 4; ++i_) {                     \
      GLD_LDS16(srcA[i_] + (size_t)(t_) * 64,                              \
                &lds[((t_) & 3) * 32768 + dchunk0 + i_ * 1024]);           \
    }                                                                      \
  }

  // prologue: A(0), A(1) in flight
  ISSUE_A(0);
  ISSUE_A(1);

  for (int t = 0; t < 32; ++t) {
    // gate: A(t) landed; A(t+1) may stay in flight (counted, no drain)
    __builtin_amdgcn_sched_barrier(0);
    if (t < 31) {
      asm volatile("s_waitcnt vmcnt(4)" ::: "memory");
    } else {
      asm volatile("s_waitcnt vmcnt(0)" ::: "memory");
    }
    __builtin_amdgcn_sched_barrier(0);
    __builtin_amdgcn_s_barrier();
    __builtin_amdgcn_sched_barrier(0);

    // prefetch A(t+2) into slot freed at the barrier above
    if (t < 30) ISSUE_A(t + 2);
    __builtin_amdgcn_sched_barrier(0);

    // B fragments for tile t: direct global->reg (compiler handles waits)
    bf16x8 bh[4], bl[4];
#pragma unroll
    for (int nj = 0; nj < 4; ++nj) {
      bh[nj] = *(const bf16x8*)(bColH[nj] + t * 32);
      bl[nj] = *(const bf16x8*)(bColL[nj] + t * 32);
    }

    const char* abuf = &lds[(t & 3) * 32768];
    __builtin_amdgcn_s_setprio(1);
#pragma unroll
    for (int mi = 0; mi < 8; ++mi) {
      bf16x8 ah = *(const bf16x8*)(abuf + offA0 + mi * 2048);
      bf16x8 al = *(const bf16x8*)(abuf + offA1 + mi * 2048);
#pragma unroll
      for (int nj = 0; nj < 4; ++nj) {
        acc[mi][nj] =
            __builtin_amdgcn_mfma_f32_16x16x32_bf16(ah, bh[nj], acc[mi][nj], 0, 0, 0);
        acc[mi][nj] =
            __builtin_amdgcn_mfma_f32_16x16x32_bf16(ah, bl[nj], acc[mi][nj], 0, 0, 0);
        acc[mi][nj] =
            __builtin_amdgcn_mfma_f32_16x16x32_bf16(al, bh[nj], acc[mi][nj], 0, 0, 0);
      }
    }
    __builtin_amdgcn_s_setprio(0);
  }
#undef ISSUE_A

  // epilogue: C/D col = lane&15 (N), row = (lane>>4)*4 + reg (M)
  const int crow = (lane >> 4) * 4;
#pragma unroll
  for (int nj = 0; nj < 4; ++nj) {
    const int col = n0 + wnb * 64 + nj * 16 + r15;
    const float bv = b2d[col];
#pragma unroll
    for (int mi = 0; mi < 8; ++mi) {
      const int rb = row0 + wm * 128 + mi * 16 + crow;
#pragma unroll
      for (int r = 0; r < 4; ++r) {
        float v = leaky(acc[mi][nj][r] + bv);
        unsigned short hi = f2bf(v);
        unsigned short lo = f2bf(v - bf2f(hi));
        const size_t o = (size_t)(rb + r) * HID + col;
        H2h[o] = (short)hi;
        H2l[o] = (short)lo;
      }
    }
  }
}

// ---------------------------------------------------------------------------
// Layer3 (MFMA): kout = H2 @ W3 + b3; fused DoPri combine / next-z.
// [R4 verbatim: 2-slot dbuf]  grid BATCH/32 = 512, 256 thr.
// ---------------------------------------------------------------------------
__global__ __launch_bounds__(256, 4) void k_l3(
    const short* __restrict__ H2h, const short* __restrict__ H2l,
    const short* __restrict__ W3Th, const short* __restrict__ W3Tl,
    const float* __restrict__ b3d, float* __restrict__ kout,
    const float* __restrict__ K0, const float* __restrict__ K1,
    const float* __restrict__ K2, const float* __restrict__ K3,
    const float* __restrict__ K4, float* __restrict__ y,
    short* __restrict__ zh, short* __restrict__ zl, int combine, float p1,
    float p2, float p3, float p4, float p5, float pc, float hb1, float hb2,
    float hb3, float hb4, float hb5, float hb6) {
  __shared__ short lds[2][4096];

  const int tid = threadIdx.x, lane = tid & 63, wave = tid >> 6;
  const int row0 = blockIdx.x * 32;
  const int wm = wave & 1, wn = wave >> 1;

  const int half = tid >> 7;
  const int idx = tid & 127;
  const int srow = idx >> 2;
  const int sd = idx & 3;
  const int slog = sd ^ ((srow >> 1) & 3);
  const short* Asrc = half ? H2l : H2h;
  const short* Bsrc = half ? W3Tl : W3Th;
  const char* aSrc = (const char*)(Asrc + (size_t)(row0 + srow) * HID) + slog * 16;
  const char* bSrc = (const char*)(Bsrc + (size_t)srow * HID) + slog * 16;
  short* aDst0 = &lds[0][half * 1024 + idx * 8];
  short* bDst0 = &lds[0][2048 + half * 1024 + idx * 8];
  short* aDst1 = &lds[1][half * 1024 + idx * 8];
  short* bDst1 = &lds[1][2048 + half * 1024 + idx * 8];

  const int r15 = lane & 15;
  const int kc = lane >> 4;
  const int aRow = wm * 16 + r15;
  const int bRow = wn * 16 + r15;
  const int aOff = aRow * 32 + (kc ^ ((aRow >> 1) & 3)) * 8;
  const int bOff = 2048 + bRow * 32 + (kc ^ ((bRow >> 1) & 3)) * 8;

  f32x4 acc = (f32x4){0.f, 0.f, 0.f, 0.f};

#define STAGE3(ad, bd, kb)          \
  {                                 \
    GLD_LDS16(aSrc + (kb), (ad));   \
    GLD_LDS16(bSrc + (kb), (bd));   \
  }

  STAGE3(aDst0, bDst0, 0);
  __syncthreads();

  for (int t = 0; t < 32; ++t) {
    const int cur = t & 1;
    if (t < 31) {
      if (cur == 0) STAGE3(aDst1, bDst1, (t + 1) * 64)
      else STAGE3(aDst0, bDst0, (t + 1) * 64)
    }
    const short* buf = lds[cur];
    bf16x8 ah = *(const bf16x8*)(buf + aOff);
    bf16x8 al = *(const bf16x8*)(buf + 1024 + aOff);
    bf16x8 bh = *(const bf16x8*)(buf + bOff);
    bf16x8 bl = *(const bf16x8*)(buf + 1024 + bOff);
    acc = __builtin_amdgcn_mfma_f32_16x16x32_bf16(ah, bh, acc, 0, 0, 0);
    acc = __builtin_amdgcn_mfma_f32_16x16x32_bf16(ah, bl, acc, 0, 0, 0);
    acc = __builtin_amdgcn_mfma_f32_16x16x32_bf16(al, bh, acc, 0, 0, 0);
    __syncthreads();
  }
#undef STAGE3

  const int c = wn * 16 + r15;
  const int rb = row0 + wm * 16 + (lane >> 4) * 4;
  const float bias = (c < LOOK) ? b3d[c] : 0.f;
#pragma unroll
  for (int r = 0; r < 4; ++r) {
    const int row = rb + r;
    const float kv = acc[r] + bias;
    float zv = 0.f;
    if (c < LOOK) {
      const size_t id = (size_t)row * LOOK + c;
      const float yv = y[id];
      if (combine) {
        float yn = yv + hb1 * K0[id] + hb2 * K1[id] + hb3 * K2[id] +
                   hb4 * K3[id] + hb5 * K4[id] + hb6 * kv;
        y[id] = yn;
        zv = yn;
      } else {
        kout[id] = kv;
        zv = yv + pc * kv;
        if (p1 != 0.f) zv += p1 * K0[id];
        if (p2 != 0.f) zv += p2 * K1[id];
        if (p3 != 0.f) zv += p3 * K2[id];
        if (p4 != 0.f) zv += p4 * K3[id];
        if (p5 != 0.f) zv += p5 * K4[id];
      }
    }
    unsigned short hi = f2bf(zv);
    unsigned short lo = f2bf(zv - bf2f(hi));
    const size_t zo = (size_t)row * 32 + c;
    zh[zo] = (short)hi;
    zl[zo] = (short)lo;
  }
}

// ---------------------------------------------------------------------------
__global__ __launch_bounds__(256) void k_readout(const float* __restrict__ y,
                                                 const float* __restrict__ Wf,
                                                 const float* __restrict__ bf,
                                                 float* __restrict__ out) {
  const int r = blockIdx.x * blockDim.x + threadIdx.x;
  if (r >= BATCH) return;
  float acc = bf[0];
#pragma unroll
  for (int c = 0; c < LOOK; ++c) acc += y[(size_t)r * LOOK + c] * Wf[c];
  out[r] = acc;
}

// ---------------------------------------------------------------------------
extern "C" void kernel_launch(void* const* d_in, const int* in_sizes, int n_in,
                              void* d_out, int out_size, void* d_ws,
                              size_t ws_size, hipStream_t stream) {
  const float* y0 = (const float*)d_in[0];
  const float* W1 = (const float*)d_in[1];
  const float* b1 = (const float*)d_in[2];
  const float* W2 = (const float*)d_in[3];
  const float* b2 = (const float*)d_in[4];
  const float* W3 = (const float*)d_in[5];
  const float* b3 = (const float*)d_in[6];
  const float* Wf = (const float*)d_in[7];
  const float* bf = (const float*)d_in[8];
  float* out = (float*)d_out;

  const size_t NY = (size_t)BATCH * LOOK;
  float* f = (float*)d_ws;
  float* y = f;
  float* kk[5];
  for (int i = 0; i < 5; ++i) kk[i] = f + NY * (1 + i);
  char* p = (char*)(f + NY * 6);
  short* zh = (short*)p; p += (size_t)BATCH * 32 * 2;
  short* zl = (short*)p; p += (size_t)BATCH * 32 * 2;
  short* H1h = (short*)p; p += (size_t)BATCH * HID * 2;
  short* H1l = (short*)p; p += (size_t)BATCH * HID * 2;
  short* H2h = (short*)p; p += (size_t)BATCH * HID * 2;
  short* H2l = (short*)p; p += (size_t)BATCH * HID * 2;
  short* W2Th = (short*)p; p += (size_t)HID * HID * 2;
  short* W2Tl = (short*)p; p += (size_t)HID * HID * 2;
  short* W1Th = (short*)p; p += (size_t)HID * 32 * 2;
  short* W1Tl = (short*)p; p += (size_t)HID * 32 * 2;
  short* W3Th = (short*)p; p += (size_t)32 * HID * 2;
  short* W3Tl = (short*)p;

  hipMemcpyAsync(y, y0, NY * sizeof(float), hipMemcpyDeviceToDevice, stream);
  k_zinit<<<dim3(BATCH * 32 / 256), 256, 0, stream>>>(y0, zh, zl);

  const double hh = 1.0 / 16.0;
  static const double A[6][5] = {
      {0, 0, 0, 0, 0},
      {1.0 / 5, 0, 0, 0, 0},
      {3.0 / 40, 9.0 / 40, 0, 0, 0},
      {44.0 / 45, -56.0 / 15, 32.0 / 9, 0, 0},
      {19372.0 / 6561, -25360.0 / 2187, 64448.0 / 6561, -212.0 / 729, 0},
      {9017.0 / 3168, -355.0 / 33, 46732.0 / 5247, 49.0 / 176,
       -5103.0 / 18656},
  };
  static const double Bb[6] = {35.0 / 384,  0,              500.0 / 1113,
                               125.0 / 192, -2187.0 / 6784, 11.0 / 84};

  const float hb1 = (float)(hh * Bb[0]);
  const float hb2 = (float)(hh * Bb[1]);
  const float hb3 = (float)(hh * Bb[2]);
  const float hb4 = (float)(hh * Bb[3]);
  const float hb5 = (float)(hh * Bb[4]);
  const float hb6 = (float)(hh * Bb[5]);

  for (int d = 0; d < DEPTH; ++d) {
    const float* W1d = W1 + (size_t)d * LOOK * HID;
    const float* b1d = b1 + (size_t)d * HID;
    const float* W2d = W2 + (size_t)d * HID * HID;
    const float* b2d = b2 + (size_t)d * HID;
    const float* W3d = W3 + (size_t)d * HID * LOOK;
    const float* b3d = b3 + (size_t)d * LOOK;

    k_w2split<<<dim3(16, 16), 256, 0, stream>>>(W2d, W2Th, W2Tl);
    k_w1t<<<dim3(128), 256, 0, stream>>>(W1d, W1Th, W1Tl);
    k_w3t<<<dim3(128), 256, 0, stream>>>(W3d, W3Th, W3Tl);

    for (int s = 0; s < NSTEPS; ++s) {
      for (int st = 0; st < 6; ++st) {
        float pv[5] = {0.f, 0.f, 0.f, 0.f, 0.f};
        float pc = 0.f;
        if (st < 5) {
          for (int jj = 0; jj < 5; ++jj)
            if (jj < st) pv[jj] = (float)(hh * A[st + 1][jj]);
          pc = (float)(hh * A[st + 1][st]);
        }
        k_l1<<<dim3(BATCH / 128, HID / 256), 512, 0, stream>>>(
            zh, zl, W1Th, W1Tl, b1d, H1h, H1l);
        k_mid<<<dim3(256), 512, 0, stream>>>(H1h, H1l, W2Th, W2Tl, b2d, H2h,
                                             H2l);
        const int comb = (st == 5) ? 1 : 0;
        float* kout = (st < 5) ? kk[st] : kk[0];
        k_l3<<<dim3(BATCH / 32), 256, 0, stream>>>(
            H2h, H2l, W3Th, W3Tl, b3d, kout, kk[0], kk[1], kk[2], kk[3],
            kk[4], y, zh, zl, comb, pv[0], pv[1], pv[2], pv[3], pv[4], pc,
            hb1, hb2, hb3, hb4, hb5, hb6);
      }
    }
  }

  k_readout<<<dim3(BATCH / 256), 256, 0, stream>>>(y, Wf, bf, out);
}

// Round 9
// 140439.050 us; speedup vs baseline: 1.1647x; 1.1647x over previous
//
#include <hip/hip_runtime.h>

#define BATCH 16384
#define LOOK 30
#define HID 1024
#define DEPTH 10
#define NSTEPS 16
#define ALPHA 0.3f

typedef short bf16x8 __attribute__((ext_vector_type(8)));
typedef float f32x4 __attribute__((ext_vector_type(4)));

__device__ __forceinline__ float leaky(float x) { return x > 0.f ? x : ALPHA * x; }

__device__ __forceinline__ unsigned short f2bf(float x) {
  unsigned u = __builtin_bit_cast(unsigned, x);
  unsigned r = u + 0x7FFFu + ((u >> 16) & 1u);
  return (unsigned short)(r >> 16);
}
__device__ __forceinline__ float bf2f(unsigned short b) {
  return __builtin_bit_cast(float, (unsigned)b << 16);
}

#define GLD_LDS16(g, l)                                        \
  __builtin_amdgcn_global_load_lds(                            \
      (const __attribute__((address_space(1))) void*)(g),      \
      (__attribute__((address_space(3))) void*)(l), 16, 0, 0)

#define SBAR()                               \
  {                                          \
    __builtin_amdgcn_sched_barrier(0);       \
    __builtin_amdgcn_s_barrier();            \
    __builtin_amdgcn_sched_barrier(0);       \
  }
#define WAIT_LGKM0()                                          \
  {                                                           \
    __builtin_amdgcn_sched_barrier(0);                        \
    asm volatile("s_waitcnt lgkmcnt(0)" ::: "memory");        \
    __builtin_amdgcn_sched_barrier(0);                        \
  }
#define WAIT_VM(n)                                            \
  {                                                           \
    __builtin_amdgcn_sched_barrier(0);                        \
    asm volatile("s_waitcnt vmcnt(" #n ")" ::: "memory");     \
    __builtin_amdgcn_sched_barrier(0);                        \
  }

// ---------------------------------------------------------------------------
// Prep: W2[k][n] -> W2T[n][k] hi/lo bf16. grid (16,16), 256 thr.
// ---------------------------------------------------------------------------
__global__ __launch_bounds__(256) void k_w2split(const float* __restrict__ W2d,
                                                 short* __restrict__ W2Th,
                                                 short* __restrict__ W2Tl) {
  __shared__ float t[64][65];
  const int kb = blockIdx.x * 64;
  const int nb = blockIdx.y * 64;
  for (int i = threadIdx.x; i < 4096; i += 256) {
    int r = i >> 6, c = i & 63;
    t[r][c] = W2d[(size_t)(kb + r) * HID + nb + c];
  }
  __syncthreads();
  for (int i = threadIdx.x; i < 4096; i += 256) {
    int r = i >> 6, c = i & 63;
    float v = t[c][r];
    unsigned short hi = f2bf(v);
    unsigned short lo = f2bf(v - bf2f(hi));
    W2Th[(size_t)(nb + r) * HID + kb + c] = (short)hi;
    W2Tl[(size_t)(nb + r) * HID + kb + c] = (short)lo;
  }
}

// Prep: W1[30][1024] -> W1T[1024 n][32 k] hi/lo (k 30,31 zero). grid 128.
__global__ __launch_bounds__(256) void k_w1t(const float* __restrict__ W1d,
                                             short* __restrict__ W1Th,
                                             short* __restrict__ W1Tl) {
  const int idx = blockIdx.x * 256 + threadIdx.x;
  if (idx >= 1024 * 32) return;
  const int n = idx >> 5, k = idx & 31;
  float v = (k < LOOK) ? W1d[(size_t)k * HID + n] : 0.f;
  unsigned short hi = f2bf(v);
  unsigned short lo = f2bf(v - bf2f(hi));
  W1Th[idx] = (short)hi;
  W1Tl[idx] = (short)lo;
}

// Prep: W3[1024][30] -> W3T[32 n][1024 k] hi/lo (n 30,31 zero). grid 128.
__global__ __launch_bounds__(256) void k_w3t(const float* __restrict__ W3d,
                                             short* __restrict__ W3Th,
                                             short* __restrict__ W3Tl) {
  const int idx = blockIdx.x * 256 + threadIdx.x;
  if (idx >= 32 * 1024) return;
  const int n = idx >> 10, k = idx & 1023;
  float v = (n < LOOK) ? W3d[(size_t)k * LOOK + n] : 0.f;
  unsigned short hi = f2bf(v);
  unsigned short lo = f2bf(v - bf2f(hi));
  W3Th[idx] = (short)hi;
  W3Tl[idx] = (short)lo;
}

// Init: z = y0 (padded to 32 cols) hi/lo. grid 2048.
__global__ __launch_bounds__(256) void k_zinit(const float* __restrict__ y0,
                                               short* __restrict__ zh,
                                               short* __restrict__ zl) {
  const int idx = blockIdx.x * 256 + threadIdx.x;
  if (idx >= BATCH * 32) return;
  const int r = idx >> 5, c = idx & 31;
  float v = (c < LOOK) ? y0[(size_t)r * LOOK + c] : 0.f;
  unsigned short hi = f2bf(v);
  unsigned short lo = f2bf(v - bf2f(hi));
  zh[idx] = (short)hi;
  zl[idx] = (short)lo;
}

// ---------------------------------------------------------------------------
// Layer1 (MFMA): H1 = leaky(z @ W1 + b1), single K-tile (K=32). [R4 verbatim]
// ---------------------------------------------------------------------------
__global__ __launch_bounds__(512, 2) void k_l1(
    const short* __restrict__ zh, const short* __restrict__ zl,
    const short* __restrict__ W1Th, const short* __restrict__ W1Tl,
    const float* __restrict__ b1d, short* __restrict__ H1h,
    short* __restrict__ H1l) {
  __shared__ short za[2][128 * 32];
  const int tid = threadIdx.x, lane = tid & 63, wave = tid >> 6;
  const int row0 = blockIdx.x * 128;
  const int n0 = blockIdx.y * 256;
  const int wm = wave >> 2, wn = wave & 3;
  const int r15 = lane & 15;
  const int bk = (lane >> 4) * 8;

  bf16x8 bh[4], bl[4];
#pragma unroll
  for (int nj = 0; nj < 4; ++nj) {
    const size_t bo = (size_t)(n0 + wn * 64 + nj * 16 + r15) * 32 + bk;
    bh[nj] = *(const bf16x8*)&W1Th[bo];
    bl[nj] = *(const bf16x8*)&W1Tl[bo];
  }

  GLD_LDS16((const char*)(zh + (size_t)row0 * 32) + tid * 16, &za[0][tid * 8]);
  GLD_LDS16((const char*)(zl + (size_t)row0 * 32) + tid * 16, &za[1][tid * 8]);
  __syncthreads();

  bf16x8 ah[4], al[4];
#pragma unroll
  for (int mi = 0; mi < 4; ++mi) {
    const int ao = (wm * 64 + mi * 16 + r15) * 32 + bk;
    ah[mi] = *(const bf16x8*)&za[0][ao];
    al[mi] = *(const bf16x8*)&za[1][ao];
  }

  f32x4 acc[4][4];
#pragma unroll
  for (int i = 0; i < 4; ++i)
#pragma unroll
    for (int j = 0; j < 4; ++j) acc[i][j] = (f32x4){0.f, 0.f, 0.f, 0.f};

#pragma unroll
  for (int mi = 0; mi < 4; ++mi)
#pragma unroll
    for (int nj = 0; nj < 4; ++nj) {
      acc[mi][nj] = __builtin_amdgcn_mfma_f32_16x16x32_bf16(ah[mi], bh[nj],
                                                            acc[mi][nj], 0, 0, 0);
      acc[mi][nj] = __builtin_amdgcn_mfma_f32_16x16x32_bf16(ah[mi], bl[nj],
                                                            acc[mi][nj], 0, 0, 0);
      acc[mi][nj] = __builtin_amdgcn_mfma_f32_16x16x32_bf16(al[mi], bh[nj],
                                                            acc[mi][nj], 0, 0, 0);
    }

  const int crow = (lane >> 4) * 4;
#pragma unroll
  for (int nj = 0; nj < 4; ++nj) {
    const int col = n0 + wn * 64 + nj * 16 + r15;
    const float bias = b1d[col];
#pragma unroll
    for (int mi = 0; mi < 4; ++mi) {
      const int rb = row0 + wm * 64 + mi * 16 + crow;
#pragma unroll
      for (int r = 0; r < 4; ++r) {
        float v = leaky(acc[mi][nj][r] + bias);
        unsigned short hi = f2bf(v);
        unsigned short lo = f2bf(v - bf2f(hi));
        const size_t o = (size_t)(rb + r) * HID + col;
        H1h[o] = (short)hi;
        H1l[o] = (short)lo;
      }
    }
  }
}

// ---------------------------------------------------------------------------
// Mid (MFMA): H2 = leaky(H1 @ W2 + b2), split-bf16 3-product.
// 256x256 tile, BK=32, 8 waves (2M x 4N), 16x16x32.
// Fine-phase counted-vmcnt schedule:
//   A: 3-slot LDS ring (3x32KB), prefetch distance 2 (issued p0/p3 of t for t+2).
//   B: single 32KB slot; consumed entirely into regs in p0; restaged for t+1
//      during p1/p2 (after p0's closing barrier).
//   4 phases/tile: {ds_read, 2 gld_lds, barrier, lgkmcnt(0), setprio1,
//                   24 MFMA, setprio0, [gate], barrier}.
//   Gate at tile end: vmcnt(2) (A(t+2)-p3 pair floats); vmcnt(0) only t=30.
// LDS: A slots @0/32768/65536, B @98304 = 128KB. grid 256, XCD swizzle.
// ---------------------------------------------------------------------------
__global__ __launch_bounds__(512, 2) void k_mid(
    const short* __restrict__ H1h, const short* __restrict__ H1l,
    const short* __restrict__ W2Th, const short* __restrict__ W2Tl,
    const float* __restrict__ b2d, short* __restrict__ H2h,
    short* __restrict__ H2l) {
  __shared__ char lds[131072];

  const int tid = threadIdx.x;
  const int lane = tid & 63;
  const int wave = tid >> 6;

  const int bid = blockIdx.x;
  const int wg = (bid & 7) * 32 + (bid >> 3);
  const int mb = wg >> 2, nb = wg & 3;
  const int row0 = mb * 256;
  const int n0 = nb * 256;
  const int wm = wave >> 2;
  const int wnb = wave & 3;
  const int r15 = lane & 15;
  const int kq = lane >> 4;
  const int l7 = lane & 7;
  const int l3 = lane >> 3;

  // staging sources (pre-swizzled): each wave stages 4 A-chunks + 4 B-chunks
  const char* srcA[4];
  const char* srcB[4];
  {
    const int s = l7 ^ l3;  // logical slot fetched into phys slot l7
    const char* baseA = (s < 4) ? (const char*)H1h : (const char*)H1l;
    const char* baseB = (s < 4) ? (const char*)W2Th : (const char*)W2Tl;
#pragma unroll
    for (int i = 0; i < 4; ++i) {
      const int c = wave * 4 + i;
      srcA[i] = baseA + (size_t)(row0 + c * 8 + l3) * 2048 + (size_t)(s & 3) * 16;
      srcB[i] = baseB + (size_t)(n0 + c * 8 + l3) * 2048 + (size_t)(s & 3) * 16;
    }
  }
  const int dA = wave * 4096;          // wave's chunk base within an A slot
  const int dB = 98304 + wave * 4096;  // wave's chunk base within the B slot

  // fragment read offsets (phys slot = log ^ (row&7); row&7 == l7)
  const int offA0 = (wm * 128 + r15) * 128 + ((0 + kq) ^ l7) * 16;
  const int offA1 = (wm * 128 + r15) * 128 + ((4 + kq) ^ l7) * 16;
  const int offB0 = 98304 + (wnb * 64 + r15) * 128 + ((0 + kq) ^ l7) * 16;
  const int offB1 = 98304 + (wnb * 64 + r15) * 128 + ((4 + kq) ^ l7) * 16;

  f32x4 acc[8][4];
#pragma unroll
  for (int i = 0; i < 8; ++i)
#pragma unroll
    for (int j = 0; j < 4; ++j) acc[i][j] = (f32x4){0.f, 0.f, 0.f, 0.f};

#define ISSUE_A2(t_, sa_, i0_)                                              \
  {                                                                         \
    GLD_LDS16(srcA[(i0_)] + (size_t)(t_) * 64,                              \
              &lds[(sa_) * 32768 + dA + (i0_) * 1024]);                     \
    GLD_LDS16(srcA[(i0_) + 1] + (size_t)(t_) * 64,                          \
              &lds[(sa_) * 32768 + dA + ((i0_) + 1) * 1024]);               \
  }
#define ISSUE_B2(t_, i0_)                                                   \
  {                                                                         \
    GLD_LDS16(srcB[(i0_)] + (size_t)(t_) * 64, &lds[dB + (i0_) * 1024]);    \
    GLD_LDS16(srcB[(i0_) + 1] + (size_t)(t_) * 64,                          \
              &lds[dB + ((i0_) + 1) * 1024]);                               \
  }

#define MFMA24(m0_, m1_, A0h, A0l, A1h, A1l)                                \
  _Pragma("unroll") for (int nj = 0; nj < 4; ++nj) {                        \
    acc[m0_][nj] = __builtin_amdgcn_mfma_f32_16x16x32_bf16(A0h, bh[nj], acc[m0_][nj], 0, 0, 0); \
    acc[m0_][nj] = __builtin_amdgcn_mfma_f32_16x16x32_bf16(A0h, bl[nj], acc[m0_][nj], 0, 0, 0); \
    acc[m0_][nj] = __builtin_amdgcn_mfma_f32_16x16x32_bf16(A0l, bh[nj], acc[m0_][nj], 0, 0, 0); \
    acc[m1_][nj] = __builtin_amdgcn_mfma_f32_16x16x32_bf16(A1h, bh[nj], acc[m1_][nj], 0, 0, 0); \
    acc[m1_][nj] = __builtin_amdgcn_mfma_f32_16x16x32_bf16(A1h, bl[nj], acc[m1_][nj], 0, 0, 0); \
    acc[m1_][nj] = __builtin_amdgcn_mfma_f32_16x16x32_bf16(A1l, bh[nj], acc[m1_][nj], 0, 0, 0); \
  }

  // prologue: A(0)->slot0, B(0), A(1)->slot1; gate A0+B0, A1 floats
  ISSUE_A2(0, 0, 0);
  ISSUE_A2(0, 0, 2);
  ISSUE_B2(0, 0);
  ISSUE_B2(0, 2);
  ISSUE_A2(1, 1, 0);
  ISSUE_A2(1, 1, 2);
  WAIT_VM(4);
  SBAR();

  int sa = 0;  // slot of tile t
  for (int t = 0; t < 32; ++t) {
    const char* As = &lds[sa * 32768];
    const int sa2 = (sa >= 1) ? sa - 1 : 2;  // slot of t+2

    bf16x8 bh[4], bl[4];

    // ---- phase 0: B all + A mi{0,1}; issue A(t+2) chunks 0,1
    {
#pragma unroll
      for (int nj = 0; nj < 4; ++nj) {
        bh[nj] = *(const bf16x8*)(lds + offB0 + nj * 2048);
        bl[nj] = *(const bf16x8*)(lds + offB1 + nj * 2048);
      }
      bf16x8 a0h = *(const bf16x8*)(As + offA0 + 0 * 2048);
      bf16x8 a0l = *(const bf16x8*)(As + offA1 + 0 * 2048);
      bf16x8 a1h = *(const bf16x8*)(As + offA0 + 1 * 2048);
      bf16x8 a1l = *(const bf16x8*)(As + offA1 + 1 * 2048);
      if (t < 30) ISSUE_A2(t + 2, sa2, 0);
      SBAR();
      WAIT_LGKM0();
      __builtin_amdgcn_s_setprio(1);
      MFMA24(0, 1, a0h, a0l, a1h, a1l);
      __builtin_amdgcn_s_setprio(0);
      SBAR();
    }
    // ---- phase 1: A mi{2,3}; issue B(t+1) chunks 0,1 (B slot free post-p0)
    {
      bf16x8 a2h = *(const bf16x8*)(As + offA0 + 2 * 2048);
      bf16x8 a2l = *(const bf16x8*)(As + offA1 + 2 * 2048);
      bf16x8 a3h = *(const bf16x8*)(As + offA0 + 3 * 2048);
      bf16x8 a3l = *(const bf16x8*)(As + offA1 + 3 * 2048);
      if (t < 31) ISSUE_B2(t + 1, 0);
      SBAR();
      WAIT_LGKM0();
      __builtin_amdgcn_s_setprio(1);
      MFMA24(2, 3, a2h, a2l, a3h, a3l);
      __builtin_amdgcn_s_setprio(0);
      SBAR();
    }
    // ---- phase 2: A mi{4,5}; issue B(t+1) chunks 2,3
    {
      bf16x8 a4h = *(const bf16x8*)(As + offA0 + 4 * 2048);
      bf16x8 a4l = *(const bf16x8*)(As + offA1 + 4 * 2048);
      bf16x8 a5h = *(const bf16x8*)(As + offA0 + 5 * 2048);
      bf16x8 a5l = *(const bf16x8*)(As + offA1 + 5 * 2048);
      if (t < 31) ISSUE_B2(t + 1, 2);
      SBAR();
      WAIT_LGKM0();
      __builtin_amdgcn_s_setprio(1);
      MFMA24(4, 5, a4h, a4l, a5h, a5l);
      __builtin_amdgcn_s_setprio(0);
      SBAR();
    }
    // ---- phase 3: A mi{6,7}; issue A(t+2) chunks 2,3; tile-end gate
    {
      bf16x8 a6h = *(const bf16x8*)(As + offA0 + 6 * 2048);
      bf16x8 a6l = *(const bf16x8*)(As + offA1 + 6 * 2048);
      bf16x8 a7h = *(const bf16x8*)(As + offA0 + 7 * 2048);
      bf16x8 a7l = *(const bf16x8*)(As + offA1 + 7 * 2048);
      if (t < 30) ISSUE_A2(t + 2, sa2, 2);
      SBAR();
      WAIT_LGKM0();
      __builtin_amdgcn_s_setprio(1);
      MFMA24(6, 7, a6h, a6l, a7h, a7l);
      __builtin_amdgcn_s_setprio(0);
      if (t < 30) {
        WAIT_VM(2);
      } else if (t == 30) {
        WAIT_VM(0);
      }
      SBAR();
    }
    sa = (sa == 2) ? 0 : sa + 1;
  }
#undef ISSUE_A2
#undef ISSUE_B2
#undef MFMA24

  // epilogue: C/D col = lane&15 (N), row = (lane>>4)*4 + reg (M)
  const int crow = (lane >> 4) * 4;
#pragma unroll
  for (int nj = 0; nj < 4; ++nj) {
    const int col = n0 + wnb * 64 + nj * 16 + r15;
    const float bv = b2d[col];
#pragma unroll
    for (int mi = 0; mi < 8; ++mi) {
      const int rb = row0 + wm * 128 + mi * 16 + crow;
#pragma unroll
      for (int r = 0; r < 4; ++r) {
        float v = leaky(acc[mi][nj][r] + bv);
        unsigned short hi = f2bf(v);
        unsigned short lo = f2bf(v - bf2f(hi));
        const size_t o = (size_t)(rb + r) * HID + col;
        H2h[o] = (short)hi;
        H2l[o] = (short)lo;
      }
    }
  }
}

// ---------------------------------------------------------------------------
// Layer3 (MFMA): kout = H2 @ W3 + b3; fused DoPri combine / next-z.
// [R4 verbatim: 2-slot dbuf]  grid BATCH/32 = 512, 256 thr.
// ---------------------------------------------------------------------------
__global__ __launch_bounds__(256, 4) void k_l3(
    const short* __restrict__ H2h, const short* __restrict__ H2l,
    const short* __restrict__ W3Th, const short* __restrict__ W3Tl,
    const float* __restrict__ b3d, float* __restrict__ kout,
    const float* __restrict__ K0, const float* __restrict__ K1,
    const float* __restrict__ K2, const float* __restrict__ K3,
    const float* __restrict__ K4, float* __restrict__ y,
    short* __restrict__ zh, short* __restrict__ zl, int combine, float p1,
    float p2, float p3, float p4, float p5, float pc, float hb1, float hb2,
    float hb3, float hb4, float hb5, float hb6) {
  __shared__ short lds[2][4096];

  const int tid = threadIdx.x, lane = tid & 63, wave = tid >> 6;
  const int row0 = blockIdx.x * 32;
  const int wm = wave & 1, wn = wave >> 1;

  const int half = tid >> 7;
  const int idx = tid & 127;
  const int srow = idx >> 2;
  const int sd = idx & 3;
  const int slog = sd ^ ((srow >> 1) & 3);
  const short* Asrc = half ? H2l : H2h;
  const short* Bsrc = half ? W3Tl : W3Th;
  const char* aSrc = (const char*)(Asrc + (size_t)(row0 + srow) * HID) + slog * 16;
  const char* bSrc = (const char*)(Bsrc + (size_t)srow * HID) + slog * 16;
  short* aDst0 = &lds[0][half * 1024 + idx * 8];
  short* bDst0 = &lds[0][2048 + half * 1024 + idx * 8];
  short* aDst1 = &lds[1][half * 1024 + idx * 8];
  short* bDst1 = &lds[1][2048 + half * 1024 + idx * 8];

  const int r15 = lane & 15;
  const int kc = lane >> 4;
  const int aRow = wm * 16 + r15;
  const int bRow = wn * 16 + r15;
  const int aOff = aRow * 32 + (kc ^ ((aRow >> 1) & 3)) * 8;
  const int bOff = 2048 + bRow * 32 + (kc ^ ((bRow >> 1) & 3)) * 8;

  f32x4 acc = (f32x4){0.f, 0.f, 0.f, 0.f};

#define STAGE3(ad, bd, kb)          \
  {                                 \
    GLD_LDS16(aSrc + (kb), (ad));   \
    GLD_LDS16(bSrc + (kb), (bd));   \
  }

  STAGE3(aDst0, bDst0, 0);
  __syncthreads();

  for (int t = 0; t < 32; ++t) {
    const int cur = t & 1;
    if (t < 31) {
      if (cur == 0) STAGE3(aDst1, bDst1, (t + 1) * 64)
      else STAGE3(aDst0, bDst0, (t + 1) * 64)
    }
    const short* buf = lds[cur];
    bf16x8 ah = *(const bf16x8*)(buf + aOff);
    bf16x8 al = *(const bf16x8*)(buf + 1024 + aOff);
    bf16x8 bh = *(const bf16x8*)(buf + bOff);
    bf16x8 bl = *(const bf16x8*)(buf + 1024 + bOff);
    acc = __builtin_amdgcn_mfma_f32_16x16x32_bf16(ah, bh, acc, 0, 0, 0);
    acc = __builtin_amdgcn_mfma_f32_16x16x32_bf16(ah, bl, acc, 0, 0, 0);
    acc = __builtin_amdgcn_mfma_f32_16x16x32_bf16(al, bh, acc, 0, 0, 0);
    __syncthreads();
  }
#undef STAGE3

  const int c = wn * 16 + r15;
  const int rb = row0 + wm * 16 + (lane >> 4) * 4;
  const float bias = (c < LOOK) ? b3d[c] : 0.f;
#pragma unroll
  for (int r = 0; r < 4; ++r) {
    const int row = rb + r;
    const float kv = acc[r] + bias;
    float zv = 0.f;
    if (c < LOOK) {
      const size_t id = (size_t)row * LOOK + c;
      const float yv = y[id];
      if (combine) {
        float yn = yv + hb1 * K0[id] + hb2 * K1[id] + hb3 * K2[id] +
                   hb4 * K3[id] + hb5 * K4[id] + hb6 * kv;
        y[id] = yn;
        zv = yn;
      } else {
        kout[id] = kv;
        zv = yv + pc * kv;
        if (p1 != 0.f) zv += p1 * K0[id];
        if (p2 != 0.f) zv += p2 * K1[id];
        if (p3 != 0.f) zv += p3 * K2[id];
        if (p4 != 0.f) zv += p4 * K3[id];
        if (p5 != 0.f) zv += p5 * K4[id];
      }
    }
    unsigned short hi = f2bf(zv);
    unsigned short lo = f2bf(zv - bf2f(hi));
    const size_t zo = (size_t)row * 32 + c;
    zh[zo] = (short)hi;
    zl[zo] = (short)lo;
  }
}

// ---------------------------------------------------------------------------
__global__ __launch_bounds__(256) void k_readout(const float* __restrict__ y,
                                                 const float* __restrict__ Wf,
                                                 const float* __restrict__ bf,
                                                 float* __restrict__ out) {
  const int r = blockIdx.x * blockDim.x + threadIdx.x;
  if (r >= BATCH) return;
  float acc = bf[0];
#pragma unroll
  for (int c = 0; c < LOOK; ++c) acc += y[(size_t)r * LOOK + c] * Wf[c];
  out[r] = acc;
}

// ---------------------------------------------------------------------------
extern "C" void kernel_launch(void* const* d_in, const int* in_sizes, int n_in,
                              void* d_out, int out_size, void* d_ws,
                              size_t ws_size, hipStream_t stream) {
  const float* y0 = (const float*)d_in[0];
  const float* W1 = (const float*)d_in[1];
  const float* b1 = (const float*)d_in[2];
  const float* W2 = (const float*)d_in[3];
  const float* b2 = (const float*)d_in[4];
  const float* W3 = (const float*)d_in[5];
  const float* b3 = (const float*)d_in[6];
  const float* Wf = (const float*)d_in[7];
  const float* bf = (const float*)d_in[8];
  float* out = (float*)d_out;

  const size_t NY = (size_t)BATCH * LOOK;
  float* f = (float*)d_ws;
  float* y = f;
  float* kk[5];
  for (int i = 0; i < 5; ++i) kk[i] = f + NY * (1 + i);
  char* p = (char*)(f + NY * 6);
  short* zh = (short*)p; p += (size_t)BATCH * 32 * 2;
  short* zl = (short*)p; p += (size_t)BATCH * 32 * 2;
  short* H1h = (short*)p; p += (size_t)BATCH * HID * 2;
  short* H1l = (short*)p; p += (size_t)BATCH * HID * 2;
  short* H2h = (short*)p; p += (size_t)BATCH * HID * 2;
  short* H2l = (short*)p; p += (size_t)BATCH * HID * 2;
  short* W2Th = (short*)p; p += (size_t)HID * HID * 2;
  short* W2Tl = (short*)p; p += (size_t)HID * HID * 2;
  short* W1Th = (short*)p; p += (size_t)HID * 32 * 2;
  short* W1Tl = (short*)p; p += (size_t)HID * 32 * 2;
  short* W3Th = (short*)p; p += (size_t)32 * HID * 2;
  short* W3Tl = (short*)p;

  hipMemcpyAsync(y, y0, NY * sizeof(float), hipMemcpyDeviceToDevice, stream);
  k_zinit<<<dim3(BATCH * 32 / 256), 256, 0, stream>>>(y0, zh, zl);

  const double hh = 1.0 / 16.0;
  static const double A[6][5] = {
      {0, 0, 0, 0, 0},
      {1.0 / 5, 0, 0, 0, 0},
      {3.0 / 40, 9.0 / 40, 0, 0, 0},
      {44.0 / 45, -56.0 / 15, 32.0 / 9, 0, 0},
      {19372.0 / 6561, -25360.0 / 2187, 64448.0 / 6561, -212.0 / 729, 0},
      {9017.0 / 3168, -355.0 / 33, 46732.0 / 5247, 49.0 / 176,
       -5103.0 / 18656},
  };
  static const double Bb[6] = {35.0 / 384,  0,              500.0 / 1113,
                               125.0 / 192, -2187.0 / 6784, 11.0 / 84};

  const float hb1 = (float)(hh * Bb[0]);
  const float hb2 = (float)(hh * Bb[1]);
  const float hb3 = (float)(hh * Bb[2]);
  const float hb4 = (float)(hh * Bb[3]);
  const float hb5 = (float)(hh * Bb[4]);
  const float hb6 = (float)(hh * Bb[5]);

  for (int d = 0; d < DEPTH; ++d) {
    const float* W1d = W1 + (size_t)d * LOOK * HID;
    const float* b1d = b1 + (size_t)d * HID;
    const float* W2d = W2 + (size_t)d * HID * HID;
    const float* b2d = b2 + (size_t)d * HID;
    const float* W3d = W3 + (size_t)d * HID * LOOK;
    const float* b3d = b3 + (size_t)d * LOOK;

    k_w2split<<<dim3(16, 16), 256, 0, stream>>>(W2d, W2Th, W2Tl);
    k_w1t<<<dim3(128), 256, 0, stream>>>(W1d, W1Th, W1Tl);
    k_w3t<<<dim3(128), 256, 0, stream>>>(W3d, W3Th, W3Tl);

    for (int s = 0; s < NSTEPS; ++s) {
      for (int st = 0; st < 6; ++st) {
        float pv[5] = {0.f, 0.f, 0.f, 0.f, 0.f};
        float pc = 0.f;
        if (st < 5) {
          for (int jj = 0; jj < 5; ++jj)
            if (jj < st) pv[jj] = (float)(hh * A[st + 1][jj]);
          pc = (float)(hh * A[st + 1][st]);
        }
        k_l1<<<dim3(BATCH / 128, HID / 256), 512, 0, stream>>>(
            zh, zl, W1Th, W1Tl, b1d, H1h, H1l);
        k_mid<<<dim3(256), 512, 0, stream>>>(H1h, H1l, W2Th, W2Tl, b2d, H2h,
                                             H2l);
        const int comb = (st == 5) ? 1 : 0;
        float* kout = (st < 5) ? kk[st] : kk[0];
        k_l3<<<dim3(BATCH / 32), 256, 0, stream>>>(
            H2h, H2l, W3Th, W3Tl, b3d, kout, kk[0], kk[1], kk[2], kk[3],
            kk[4], y, zh, zl, comb, pv[0], pv[1], pv[2], pv[3], pv[4], pc,
            hb1, hb2, hb3, hb4, hb5, hb6);
      }
    }
  }

  k_readout<<<dim3(BATCH / 256), 256, 0, stream>>>(y, Wf, bf, out);
}

// Round 10
// 130677.612 us; speedup vs baseline: 1.2517x; 1.0747x over previous
//
#include <hip/hip_runtime.h>

#define BATCH 16384
#define LOOK 30
#define HID 1024
#define DEPTH 10
#define NSTEPS 16
#define ALPHA 0.3f

typedef short bf16x8 __attribute__((ext_vector_type(8)));
typedef float f32x4 __attribute__((ext_vector_type(4)));

__device__ __forceinline__ float leaky(float x) { return x > 0.f ? x : ALPHA * x; }

__device__ __forceinline__ unsigned short f2bf(float x) {
  unsigned u = __builtin_bit_cast(unsigned, x);
  unsigned r = u + 0x7FFFu + ((u >> 16) & 1u);
  return (unsigned short)(r >> 16);
}
__device__ __forceinline__ float bf2f(unsigned short b) {
  return __builtin_bit_cast(float, (unsigned)b << 16);
}

#define GLD_LDS16(g, l)                                        \
  __builtin_amdgcn_global_load_lds(                            \
      (const __attribute__((address_space(1))) void*)(g),      \
      (__attribute__((address_space(3))) void*)(l), 16, 0, 0)

// ---------------------------------------------------------------------------
// Prep: W2[k][n] -> W2T[n][k] hi/lo bf16. grid (16,16), 256 thr.
// ---------------------------------------------------------------------------
__global__ __launch_bounds__(256) void k_w2split(const float* __restrict__ W2d,
                                                 short* __restrict__ W2Th,
                                                 short* __restrict__ W2Tl) {
  __shared__ float t[64][65];
  const int kb = blockIdx.x * 64;
  const int nb = blockIdx.y * 64;
  for (int i = threadIdx.x; i < 4096; i += 256) {
    int r = i >> 6, c = i & 63;
    t[r][c] = W2d[(size_t)(kb + r) * HID + nb + c];
  }
  __syncthreads();
  for (int i = threadIdx.x; i < 4096; i += 256) {
    int r = i >> 6, c = i & 63;
    float v = t[c][r];
    unsigned short hi = f2bf(v);
    unsigned short lo = f2bf(v - bf2f(hi));
    W2Th[(size_t)(nb + r) * HID + kb + c] = (short)hi;
    W2Tl[(size_t)(nb + r) * HID + kb + c] = (short)lo;
  }
}

// Prep (ALL depths): W1[d][30][1024] -> W1T[d][1024 n][32 k] hi/lo.
// grid DEPTH*1024*32/256 = 1280.
__global__ __launch_bounds__(256) void k_w1t_all(const float* __restrict__ W1,
                                                 short* __restrict__ W1Th,
                                                 short* __restrict__ W1Tl) {
  const int idx = blockIdx.x * 256 + threadIdx.x;
  if (idx >= DEPTH * 1024 * 32) return;
  const int d = idx >> 15;
  const int rem = idx & 32767;
  const int n = rem >> 5, k = rem & 31;
  float v = (k < LOOK) ? W1[(size_t)d * LOOK * HID + (size_t)k * HID + n] : 0.f;
  unsigned short hi = f2bf(v);
  unsigned short lo = f2bf(v - bf2f(hi));
  W1Th[idx] = (short)hi;
  W1Tl[idx] = (short)lo;
}

// Prep: W3[1024][30] -> W3T[32 n][1024 k] hi/lo (n 30,31 zero). grid 128.
__global__ __launch_bounds__(256) void k_w3t(const float* __restrict__ W3d,
                                             short* __restrict__ W3Th,
                                             short* __restrict__ W3Tl) {
  const int idx = blockIdx.x * 256 + threadIdx.x;
  if (idx >= 32 * 1024) return;
  const int n = idx >> 10, k = idx & 1023;
  float v = (n < LOOK) ? W3d[(size_t)k * LOOK + n] : 0.f;
  unsigned short hi = f2bf(v);
  unsigned short lo = f2bf(v - bf2f(hi));
  W3Th[idx] = (short)hi;
  W3Tl[idx] = (short)lo;
}

// Init: z = y0 (padded to 32 cols) hi/lo. grid 2048.
__global__ __launch_bounds__(256) void k_zinit(const float* __restrict__ y0,
                                               short* __restrict__ zh,
                                               short* __restrict__ zl) {
  const int idx = blockIdx.x * 256 + threadIdx.x;
  if (idx >= BATCH * 32) return;
  const int r = idx >> 5, c = idx & 31;
  float v = (c < LOOK) ? y0[(size_t)r * LOOK + c] : 0.f;
  unsigned short hi = f2bf(v);
  unsigned short lo = f2bf(v - bf2f(hi));
  zh[idx] = (short)hi;
  zl[idx] = (short)lo;
}

// ---------------------------------------------------------------------------
// Layer1 standalone (first eval only): H1 = leaky(z @ W1 + b1). [R4 verbatim]
// ---------------------------------------------------------------------------
__global__ __launch_bounds__(512, 2) void k_l1(
    const short* __restrict__ zh, const short* __restrict__ zl,
    const short* __restrict__ W1Th, const short* __restrict__ W1Tl,
    const float* __restrict__ b1d, short* __restrict__ H1h,
    short* __restrict__ H1l) {
  __shared__ short za[2][128 * 32];
  const int tid = threadIdx.x, lane = tid & 63, wave = tid >> 6;
  const int row0 = blockIdx.x * 128;
  const int n0 = blockIdx.y * 256;
  const int wm = wave >> 2, wn = wave & 3;
  const int r15 = lane & 15;
  const int bk = (lane >> 4) * 8;

  bf16x8 bh[4], bl[4];
#pragma unroll
  for (int nj = 0; nj < 4; ++nj) {
    const size_t bo = (size_t)(n0 + wn * 64 + nj * 16 + r15) * 32 + bk;
    bh[nj] = *(const bf16x8*)&W1Th[bo];
    bl[nj] = *(const bf16x8*)&W1Tl[bo];
  }

  GLD_LDS16((const char*)(zh + (size_t)row0 * 32) + tid * 16, &za[0][tid * 8]);
  GLD_LDS16((const char*)(zl + (size_t)row0 * 32) + tid * 16, &za[1][tid * 8]);
  __syncthreads();

  bf16x8 ah[4], al[4];
#pragma unroll
  for (int mi = 0; mi < 4; ++mi) {
    const int ao = (wm * 64 + mi * 16 + r15) * 32 + bk;
    ah[mi] = *(const bf16x8*)&za[0][ao];
    al[mi] = *(const bf16x8*)&za[1][ao];
  }

  f32x4 acc[4][4];
#pragma unroll
  for (int i = 0; i < 4; ++i)
#pragma unroll
    for (int j = 0; j < 4; ++j) acc[i][j] = (f32x4){0.f, 0.f, 0.f, 0.f};

#pragma unroll
  for (int mi = 0; mi < 4; ++mi)
#pragma unroll
    for (int nj = 0; nj < 4; ++nj) {
      acc[mi][nj] = __builtin_amdgcn_mfma_f32_16x16x32_bf16(ah[mi], bh[nj],
                                                            acc[mi][nj], 0, 0, 0);
      acc[mi][nj] = __builtin_amdgcn_mfma_f32_16x16x32_bf16(ah[mi], bl[nj],
                                                            acc[mi][nj], 0, 0, 0);
      acc[mi][nj] = __builtin_amdgcn_mfma_f32_16x16x32_bf16(al[mi], bh[nj],
                                                            acc[mi][nj], 0, 0, 0);
    }

  const int crow = (lane >> 4) * 4;
#pragma unroll
  for (int nj = 0; nj < 4; ++nj) {
    const int col = n0 + wn * 64 + nj * 16 + r15;
    const float bias = b1d[col];
#pragma unroll
    for (int mi = 0; mi < 4; ++mi) {
      const int rb = row0 + wm * 64 + mi * 16 + crow;
#pragma unroll
      for (int r = 0; r < 4; ++r) {
        float v = leaky(acc[mi][nj][r] + bias);
        unsigned short hi = f2bf(v);
        unsigned short lo = f2bf(v - bf2f(hi));
        const size_t o = (size_t)(rb + r) * HID + col;
        H1h[o] = (short)hi;
        H1l[o] = (short)lo;
      }
    }
  }
}

// ---------------------------------------------------------------------------
// Mid (MFMA): H2 = leaky(H1 @ W2 + b2), split-bf16 3-product. [R4 verbatim]
// 256x256 tile, BK=32, 8 waves (2M x 4N), dbuf, 1 barrier/tile (impl. drain).
// ---------------------------------------------------------------------------
__global__ __launch_bounds__(512, 2) void k_mid(
    const short* __restrict__ H1h, const short* __restrict__ H1l,
    const short* __restrict__ W2Th, const short* __restrict__ W2Tl,
    const float* __restrict__ b2d, short* __restrict__ H2h,
    short* __restrict__ H2l) {
  __shared__ char lds[131072];

  const int tid = threadIdx.x;
  const int lane = tid & 63;
  const int wave = tid >> 6;

  const int bid = blockIdx.x;
  const int wg = (bid & 7) * 32 + (bid >> 3);
  const int mb = wg >> 2, nb = wg & 3;
  const int row0 = mb * 256;
  const int n0 = nb * 256;
  const int wm = wave >> 2;
  const int wnb = wave & 3;
  const int r15 = lane & 15;
  const int kq = lane >> 4;
  const int l7 = lane & 7;
  const int l3 = lane >> 3;

  const char* srcB[8];
  {
    const int s = l7 ^ l3;
    const char* hsrc;
    const char* lsrc;
    int rbase;
    if (wave < 4) {
      hsrc = (const char*)H1h;
      lsrc = (const char*)H1l;
      rbase = row0;
    } else {
      hsrc = (const char*)W2Th;
      lsrc = (const char*)W2Tl;
      rbase = n0;
    }
    const char* base = (s < 4) ? hsrc : lsrc;
#pragma unroll
    for (int i = 0; i < 8; ++i) {
      const int c = wave * 8 + i;
      const int rloc = (c & 31) * 8 + l3;
      srcB[i] = base + (size_t)(rbase + rloc) * 2048 + (size_t)(s & 3) * 16;
    }
  }
  const int dchunk0 = wave * 8192;

  const int offA0 = (wm * 128 + r15) * 128 + ((0 + kq) ^ l7) * 16;
  const int offA1 = (wm * 128 + r15) * 128 + ((4 + kq) ^ l7) * 16;
  const int offB0 = 32768 + (wnb * 64 + r15) * 128 + ((0 + kq) ^ l7) * 16;
  const int offB1 = 32768 + (wnb * 64 + r15) * 128 + ((4 + kq) ^ l7) * 16;

  f32x4 acc[8][4];
#pragma unroll
  for (int i = 0; i < 8; ++i)
#pragma unroll
    for (int j = 0; j < 4; ++j) acc[i][j] = (f32x4){0.f, 0.f, 0.f, 0.f};

#define STAGE(buf, kb)                                                   \
  {                                                                      \
    _Pragma("unroll") for (int i = 0; i < 8; ++i) {                      \
      GLD_LDS16(srcB[i] + (kb), &lds[(buf)*65536 + dchunk0 + i * 1024]); \
    }                                                                    \
  }

  STAGE(0, 0);
  __syncthreads();

  int cur = 0;
  for (int t = 0; t < 32; ++t) {
    if (t < 31) STAGE(cur ^ 1, (t + 1) * 64);

    const char* buf = &lds[cur * 65536];
    bf16x8 bh[4], bl[4];
#pragma unroll
    for (int nj = 0; nj < 4; ++nj) {
      bh[nj] = *(const bf16x8*)(buf + offB0 + nj * 2048);
      bl[nj] = *(const bf16x8*)(buf + offB1 + nj * 2048);
    }
#pragma unroll
    for (int mi = 0; mi < 8; ++mi) {
      bf16x8 ah = *(const bf16x8*)(buf + offA0 + mi * 2048);
      bf16x8 al = *(const bf16x8*)(buf + offA1 + mi * 2048);
#pragma unroll
      for (int nj = 0; nj < 4; ++nj) {
        acc[mi][nj] =
            __builtin_amdgcn_mfma_f32_16x16x32_bf16(ah, bh[nj], acc[mi][nj], 0, 0, 0);
        acc[mi][nj] =
            __builtin_amdgcn_mfma_f32_16x16x32_bf16(ah, bl[nj], acc[mi][nj], 0, 0, 0);
        acc[mi][nj] =
            __builtin_amdgcn_mfma_f32_16x16x32_bf16(al, bh[nj], acc[mi][nj], 0, 0, 0);
      }
    }
    __syncthreads();
    cur ^= 1;
  }
#undef STAGE

  const int crow = (lane >> 4) * 4;
#pragma unroll
  for (int nj = 0; nj < 4; ++nj) {
    const int col = n0 + wnb * 64 + nj * 16 + r15;
    const float bv = b2d[col];
#pragma unroll
    for (int mi = 0; mi < 8; ++mi) {
      const int rb = row0 + wm * 128 + mi * 16 + crow;
#pragma unroll
      for (int r = 0; r < 4; ++r) {
        float v = leaky(acc[mi][nj][r] + bv);
        unsigned short hi = f2bf(v);
        unsigned short lo = f2bf(v - bf2f(hi));
        const size_t o = (size_t)(rb + r) * HID + col;
        H2h[o] = (short)hi;
        H2l[o] = (short)lo;
      }
    }
  }
}

// ---------------------------------------------------------------------------
// Fused Layer3 + next-stage Layer1, per 32-row slice. grid 512, 256 thr.
// Part 1 (R4 k_l3): kout = H2 @ W3 + b3; DoPri combine / next-z -> z in LDS.
// Part 2: H1(next) = leaky(z @ W1next + b1next), z frags from LDS,
//         W1T frags global (L2-hot). 96 MFMA/wave.
// ---------------------------------------------------------------------------
__global__ __launch_bounds__(256, 2) void k_l3l1(
    const short* __restrict__ H2h, const short* __restrict__ H2l,
    const short* __restrict__ W3Th, const short* __restrict__ W3Tl,
    const float* __restrict__ b3d, float* __restrict__ kout,
    const float* __restrict__ K0, const float* __restrict__ K1,
    const float* __restrict__ K2, const float* __restrict__ K3,
    const float* __restrict__ K4, float* __restrict__ y, int combine,
    float p1, float p2, float p3, float p4, float p5, float pc, float hb1,
    float hb2, float hb3, float hb4, float hb5, float hb6,
    const short* __restrict__ W1Tnh, const short* __restrict__ W1Tnl,
    const float* __restrict__ b1n, short* __restrict__ H1h,
    short* __restrict__ H1l) {
  __shared__ short lds[2][4096];
  __shared__ short zs[2][32][40];  // hi/lo z, 80B row stride (bank-spread)

  const int tid = threadIdx.x, lane = tid & 63, wave = tid >> 6;
  const int row0 = blockIdx.x * 32;
  const int wm = wave & 1, wn = wave >> 1;

  // ---- Part 1: kout = H2 @ W3 + b3 (R4 k_l3 verbatim)
  const int half = tid >> 7;
  const int idx = tid & 127;
  const int srow = idx >> 2;
  const int sd = idx & 3;
  const int slog = sd ^ ((srow >> 1) & 3);
  const short* Asrc = half ? H2l : H2h;
  const short* Bsrc = half ? W3Tl : W3Th;
  const char* aSrc = (const char*)(Asrc + (size_t)(row0 + srow) * HID) + slog * 16;
  const char* bSrc = (const char*)(Bsrc + (size_t)srow * HID) + slog * 16;
  short* aDst0 = &lds[0][half * 1024 + idx * 8];
  short* bDst0 = &lds[0][2048 + half * 1024 + idx * 8];
  short* aDst1 = &lds[1][half * 1024 + idx * 8];
  short* bDst1 = &lds[1][2048 + half * 1024 + idx * 8];

  const int r15 = lane & 15;
  const int kc = lane >> 4;
  const int aRow = wm * 16 + r15;
  const int bRow = wn * 16 + r15;
  const int aOff = aRow * 32 + (kc ^ ((aRow >> 1) & 3)) * 8;
  const int bOff = 2048 + bRow * 32 + (kc ^ ((bRow >> 1) & 3)) * 8;

  f32x4 acc = (f32x4){0.f, 0.f, 0.f, 0.f};

#define STAGE3(ad, bd, kb)          \
  {                                 \
    GLD_LDS16(aSrc + (kb), (ad));   \
    GLD_LDS16(bSrc + (kb), (bd));   \
  }

  STAGE3(aDst0, bDst0, 0);
  __syncthreads();

  for (int t = 0; t < 32; ++t) {
    const int cur = t & 1;
    if (t < 31) {
      if (cur == 0) STAGE3(aDst1, bDst1, (t + 1) * 64)
      else STAGE3(aDst0, bDst0, (t + 1) * 64)
    }
    const short* buf = lds[cur];
    bf16x8 ah = *(const bf16x8*)(buf + aOff);
    bf16x8 al = *(const bf16x8*)(buf + 1024 + aOff);
    bf16x8 bh = *(const bf16x8*)(buf + bOff);
    bf16x8 bl = *(const bf16x8*)(buf + 1024 + bOff);
    acc = __builtin_amdgcn_mfma_f32_16x16x32_bf16(ah, bh, acc, 0, 0, 0);
    acc = __builtin_amdgcn_mfma_f32_16x16x32_bf16(ah, bl, acc, 0, 0, 0);
    acc = __builtin_amdgcn_mfma_f32_16x16x32_bf16(al, bh, acc, 0, 0, 0);
    __syncthreads();
  }
#undef STAGE3

  // epilogue: DoPri combine / z into LDS
  {
    const int c = wn * 16 + r15;
    const int rb = wm * 16 + (lane >> 4) * 4;  // local row
    const float bias = (c < LOOK) ? b3d[c] : 0.f;
#pragma unroll
    for (int r = 0; r < 4; ++r) {
      const int rloc = rb + r;
      const int row = row0 + rloc;
      const float kv = acc[r] + bias;
      float zv = 0.f;
      if (c < LOOK) {
        const size_t id = (size_t)row * LOOK + c;
        const float yv = y[id];
        if (combine) {
          float yn = yv + hb1 * K0[id] + hb2 * K1[id] + hb3 * K2[id] +
                     hb4 * K3[id] + hb5 * K4[id] + hb6 * kv;
          y[id] = yn;
          zv = yn;
        } else {
          kout[id] = kv;
          zv = yv + pc * kv;
          if (p1 != 0.f) zv += p1 * K0[id];
          if (p2 != 0.f) zv += p2 * K1[id];
          if (p3 != 0.f) zv += p3 * K2[id];
          if (p4 != 0.f) zv += p4 * K3[id];
          if (p5 != 0.f) zv += p5 * K4[id];
        }
      }
      unsigned short hi = f2bf(zv);
      unsigned short lo = f2bf(zv - bf2f(hi));
      zs[0][rloc][c] = (short)hi;
      zs[1][rloc][c] = (short)lo;
    }
  }
  __syncthreads();

  // ---- Part 2: H1(next) = leaky(z @ W1next + b1next)
  // wave handles cols [wave*256, wave*256+256); A-frags from zs.
  bf16x8 zfh[2], zfl[2];
#pragma unroll
  for (int mi = 0; mi < 2; ++mi) {
    zfh[mi] = *(const bf16x8*)&zs[0][mi * 16 + r15][kc * 8];
    zfl[mi] = *(const bf16x8*)&zs[1][mi * 16 + r15][kc * 8];
  }
  const int crow = (lane >> 4) * 4;
#pragma unroll
  for (int nj = 0; nj < 16; ++nj) {
    const int col = wave * 256 + nj * 16 + r15;
    const size_t bo = (size_t)col * 32 + kc * 8;
    bf16x8 bh = *(const bf16x8*)&W1Tnh[bo];
    bf16x8 bl = *(const bf16x8*)&W1Tnl[bo];
    f32x4 a0 = (f32x4){0.f, 0.f, 0.f, 0.f};
    f32x4 a1 = (f32x4){0.f, 0.f, 0.f, 0.f};
    a0 = __builtin_amdgcn_mfma_f32_16x16x32_bf16(zfh[0], bh, a0, 0, 0, 0);
    a0 = __builtin_amdgcn_mfma_f32_16x16x32_bf16(zfh[0], bl, a0, 0, 0, 0);
    a0 = __builtin_amdgcn_mfma_f32_16x16x32_bf16(zfl[0], bh, a0, 0, 0, 0);
    a1 = __builtin_amdgcn_mfma_f32_16x16x32_bf16(zfh[1], bh, a1, 0, 0, 0);
    a1 = __builtin_amdgcn_mfma_f32_16x16x32_bf16(zfh[1], bl, a1, 0, 0, 0);
    a1 = __builtin_amdgcn_mfma_f32_16x16x32_bf16(zfl[1], bh, a1, 0, 0, 0);
    const float bias = b1n[col];
#pragma unroll
    for (int mi = 0; mi < 2; ++mi) {
      const f32x4 av = mi ? a1 : a0;
      const int rbase = row0 + mi * 16 + crow;
#pragma unroll
      for (int r = 0; r < 4; ++r) {
        float v = leaky(av[r] + bias);
        unsigned short hi = f2bf(v);
        unsigned short lo = f2bf(v - bf2f(hi));
        const size_t o = (size_t)(rbase + r) * HID + col;
        H1h[o] = (short)hi;
        H1l[o] = (short)lo;
      }
    }
  }
}

// ---------------------------------------------------------------------------
__global__ __launch_bounds__(256) void k_readout(const float* __restrict__ y,
                                                 const float* __restrict__ Wf,
                                                 const float* __restrict__ bf,
                                                 float* __restrict__ out) {
  const int r = blockIdx.x * blockDim.x + threadIdx.x;
  if (r >= BATCH) return;
  float acc = bf[0];
#pragma unroll
  for (int c = 0; c < LOOK; ++c) acc += y[(size_t)r * LOOK + c] * Wf[c];
  out[r] = acc;
}

// ---------------------------------------------------------------------------
extern "C" void kernel_launch(void* const* d_in, const int* in_sizes, int n_in,
                              void* d_out, int out_size, void* d_ws,
                              size_t ws_size, hipStream_t stream) {
  const float* y0 = (const float*)d_in[0];
  const float* W1 = (const float*)d_in[1];
  const float* b1 = (const float*)d_in[2];
  const float* W2 = (const float*)d_in[3];
  const float* b2 = (const float*)d_in[4];
  const float* W3 = (const float*)d_in[5];
  const float* b3 = (const float*)d_in[6];
  const float* Wf = (const float*)d_in[7];
  const float* bf = (const float*)d_in[8];
  float* out = (float*)d_out;

  const size_t NY = (size_t)BATCH * LOOK;
  float* f = (float*)d_ws;
  float* y = f;
  float* kk[5];
  for (int i = 0; i < 5; ++i) kk[i] = f + NY * (1 + i);
  char* p = (char*)(f + NY * 6);
  short* zh = (short*)p; p += (size_t)BATCH * 32 * 2;
  short* zl = (short*)p; p += (size_t)BATCH * 32 * 2;
  short* H1h = (short*)p; p += (size_t)BATCH * HID * 2;
  short* H1l = (short*)p; p += (size_t)BATCH * HID * 2;
  short* H2h = (short*)p; p += (size_t)BATCH * HID * 2;
  short* H2l = (short*)p; p += (size_t)BATCH * HID * 2;
  short* W2Th = (short*)p; p += (size_t)HID * HID * 2;
  short* W2Tl = (short*)p; p += (size_t)HID * HID * 2;
  short* W1Th = (short*)p; p += (size_t)DEPTH * HID * 32 * 2;
  short* W1Tl = (short*)p; p += (size_t)DEPTH * HID * 32 * 2;
  short* W3Th = (short*)p; p += (size_t)32 * HID * 2;
  short* W3Tl = (short*)p;

  hipMemcpyAsync(y, y0, NY * sizeof(float), hipMemcpyDeviceToDevice, stream);

  // all-depth W1 transpose/split, z init, first H1
  k_w1t_all<<<dim3(DEPTH * 1024 * 32 / 256), 256, 0, stream>>>(W1, W1Th, W1Tl);
  k_zinit<<<dim3(BATCH * 32 / 256), 256, 0, stream>>>(y0, zh, zl);
  k_l1<<<dim3(BATCH / 128, HID / 256), 512, 0, stream>>>(zh, zl, W1Th, W1Tl,
                                                         b1, H1h, H1l);

  const double hh = 1.0 / 16.0;
  static const double A[6][5] = {
      {0, 0, 0, 0, 0},
      {1.0 / 5, 0, 0, 0, 0},
      {3.0 / 40, 9.0 / 40, 0, 0, 0},
      {44.0 / 45, -56.0 / 15, 32.0 / 9, 0, 0},
      {19372.0 / 6561, -25360.0 / 2187, 64448.0 / 6561, -212.0 / 729, 0},
      {9017.0 / 3168, -355.0 / 33, 46732.0 / 5247, 49.0 / 176,
       -5103.0 / 18656},
  };
  static const double Bb[6] = {35.0 / 384,  0,              500.0 / 1113,
                               125.0 / 192, -2187.0 / 6784, 11.0 / 84};

  const float hb1 = (float)(hh * Bb[0]);
  const float hb2 = (float)(hh * Bb[1]);
  const float hb3 = (float)(hh * Bb[2]);
  const float hb4 = (float)(hh * Bb[3]);
  const float hb5 = (float)(hh * Bb[4]);
  const float hb6 = (float)(hh * Bb[5]);

  for (int d = 0; d < DEPTH; ++d) {
    const float* W2d = W2 + (size_t)d * HID * HID;
    const float* b2d = b2 + (size_t)d * HID;
    const float* W3d = W3 + (size_t)d * HID * LOOK;
    const float* b3d = b3 + (size_t)d * LOOK;

    k_w2split<<<dim3(16, 16), 256, 0, stream>>>(W2d, W2Th, W2Tl);
    k_w3t<<<dim3(128), 256, 0, stream>>>(W3d, W3Th, W3Tl);

    for (int s = 0; s < NSTEPS; ++s) {
      for (int st = 0; st < 6; ++st) {
        float pv[5] = {0.f, 0.f, 0.f, 0.f, 0.f};
        float pc = 0.f;
        if (st < 5) {
          for (int jj = 0; jj < 5; ++jj)
            if (jj < st) pv[jj] = (float)(hh * A[st + 1][jj]);
          pc = (float)(hh * A[st + 1][st]);
        }
        // depth of the NEXT drift eval (l1 part of the fused kernel)
        int dn = d;
        if (st == 5 && s == NSTEPS - 1) dn = (d + 1 < DEPTH) ? d + 1 : d;
        const short* W1Tnh = W1Th + (size_t)dn * HID * 32;
        const short* W1Tnl = W1Tl + (size_t)dn * HID * 32;
        const float* b1n = b1 + (size_t)dn * HID;

        k_mid<<<dim3(256), 512, 0, stream>>>(H1h, H1l, W2Th, W2Tl, b2d, H2h,
                                             H2l);
        const int comb = (st == 5) ? 1 : 0;
        float* kout = (st < 5) ? kk[st] : kk[0];
        k_l3l1<<<dim3(BATCH / 32), 256, 0, stream>>>(
            H2h, H2l, W3Th, W3Tl, b3d, kout, kk[0], kk[1], kk[2], kk[3],
            kk[4], y, comb, pv[0], pv[1], pv[2], pv[3], pv[4], pc, hb1, hb2,
            hb3, hb4, hb5, hb6, W1Tnh, W1Tnl, b1n, H1h, H1l);
      }
    }
  }

  k_readout<<<dim3(BATCH / 256), 256, 0, stream>>>(y, Wf, bf, out);
}

// Round 11
// 130668.408 us; speedup vs baseline: 1.2518x; 1.0001x over previous
//
#include <hip/hip_runtime.h>

#define BATCH 16384
#define LOOK 30
#define HID 1024
#define DEPTH 10
#define NSTEPS 16
#define ALPHA 0.3f

typedef short bf16x8 __attribute__((ext_vector_type(8)));
typedef float f32x4 __attribute__((ext_vector_type(4)));

__device__ __forceinline__ float leaky(float x) { return x > 0.f ? x : ALPHA * x; }

__device__ __forceinline__ unsigned short f2bf(float x) {
  unsigned u = __builtin_bit_cast(unsigned, x);
  unsigned r = u + 0x7FFFu + ((u >> 16) & 1u);
  return (unsigned short)(r >> 16);
}
__device__ __forceinline__ float bf2f(unsigned short b) {
  return __builtin_bit_cast(float, (unsigned)b << 16);
}

#define GLD_LDS16(g, l)                                        \
  __builtin_amdgcn_global_load_lds(                            \
      (const __attribute__((address_space(1))) void*)(g),      \
      (__attribute__((address_space(3))) void*)(l), 16, 0, 0)

// ---------------------------------------------------------------------------
// Prep: W2[k][n] -> W2T[n][k] hi/lo bf16. grid (16,16), 256 thr.
// ---------------------------------------------------------------------------
__global__ __launch_bounds__(256) void k_w2split(const float* __restrict__ W2d,
                                                 short* __restrict__ W2Th,
                                                 short* __restrict__ W2Tl) {
  __shared__ float t[64][65];
  const int kb = blockIdx.x * 64;
  const int nb = blockIdx.y * 64;
  for (int i = threadIdx.x; i < 4096; i += 256) {
    int r = i >> 6, c = i & 63;
    t[r][c] = W2d[(size_t)(kb + r) * HID + nb + c];
  }
  __syncthreads();
  for (int i = threadIdx.x; i < 4096; i += 256) {
    int r = i >> 6, c = i & 63;
    float v = t[c][r];
    unsigned short hi = f2bf(v);
    unsigned short lo = f2bf(v - bf2f(hi));
    W2Th[(size_t)(nb + r) * HID + kb + c] = (short)hi;
    W2Tl[(size_t)(nb + r) * HID + kb + c] = (short)lo;
  }
}

// Prep (ALL depths): W1[d][30][1024] -> W1T[d][1024 n][32 k] hi/lo. grid 1280.
__global__ __launch_bounds__(256) void k_w1t_all(const float* __restrict__ W1,
                                                 short* __restrict__ W1Th,
                                                 short* __restrict__ W1Tl) {
  const int idx = blockIdx.x * 256 + threadIdx.x;
  if (idx >= DEPTH * 1024 * 32) return;
  const int d = idx >> 15;
  const int rem = idx & 32767;
  const int n = rem >> 5, k = rem & 31;
  float v = (k < LOOK) ? W1[(size_t)d * LOOK * HID + (size_t)k * HID + n] : 0.f;
  unsigned short hi = f2bf(v);
  unsigned short lo = f2bf(v - bf2f(hi));
  W1Th[idx] = (short)hi;
  W1Tl[idx] = (short)lo;
}

// Prep: W3[1024][30] -> W3T[32 n][1024 k] hi/lo (n 30,31 zero). grid 128.
__global__ __launch_bounds__(256) void k_w3t(const float* __restrict__ W3d,
                                             short* __restrict__ W3Th,
                                             short* __restrict__ W3Tl) {
  const int idx = blockIdx.x * 256 + threadIdx.x;
  if (idx >= 32 * 1024) return;
  const int n = idx >> 10, k = idx & 1023;
  float v = (n < LOOK) ? W3d[(size_t)k * LOOK + n] : 0.f;
  unsigned short hi = f2bf(v);
  unsigned short lo = f2bf(v - bf2f(hi));
  W3Th[idx] = (short)hi;
  W3Tl[idx] = (short)lo;
}

// Init: z = y0 (padded to 32 cols) hi/lo. grid 2048.
__global__ __launch_bounds__(256) void k_zinit(const float* __restrict__ y0,
                                               short* __restrict__ zh,
                                               short* __restrict__ zl) {
  const int idx = blockIdx.x * 256 + threadIdx.x;
  if (idx >= BATCH * 32) return;
  const int r = idx >> 5, c = idx & 31;
  float v = (c < LOOK) ? y0[(size_t)r * LOOK + c] : 0.f;
  unsigned short hi = f2bf(v);
  unsigned short lo = f2bf(v - bf2f(hi));
  zh[idx] = (short)hi;
  zl[idx] = (short)lo;
}

// ---------------------------------------------------------------------------
// Layer1 standalone (first eval only): H1 = leaky(z @ W1 + b1). [R4 verbatim]
// ---------------------------------------------------------------------------
__global__ __launch_bounds__(512, 2) void k_l1(
    const short* __restrict__ zh, const short* __restrict__ zl,
    const short* __restrict__ W1Th, const short* __restrict__ W1Tl,
    const float* __restrict__ b1d, short* __restrict__ H1h,
    short* __restrict__ H1l) {
  __shared__ short za[2][128 * 32];
  const int tid = threadIdx.x, lane = tid & 63, wave = tid >> 6;
  const int row0 = blockIdx.x * 128;
  const int n0 = blockIdx.y * 256;
  const int wm = wave >> 2, wn = wave & 3;
  const int r15 = lane & 15;
  const int bk = (lane >> 4) * 8;

  bf16x8 bh[4], bl[4];
#pragma unroll
  for (int nj = 0; nj < 4; ++nj) {
    const size_t bo = (size_t)(n0 + wn * 64 + nj * 16 + r15) * 32 + bk;
    bh[nj] = *(const bf16x8*)&W1Th[bo];
    bl[nj] = *(const bf16x8*)&W1Tl[bo];
  }

  GLD_LDS16((const char*)(zh + (size_t)row0 * 32) + tid * 16, &za[0][tid * 8]);
  GLD_LDS16((const char*)(zl + (size_t)row0 * 32) + tid * 16, &za[1][tid * 8]);
  __syncthreads();

  bf16x8 ah[4], al[4];
#pragma unroll
  for (int mi = 0; mi < 4; ++mi) {
    const int ao = (wm * 64 + mi * 16 + r15) * 32 + bk;
    ah[mi] = *(const bf16x8*)&za[0][ao];
    al[mi] = *(const bf16x8*)&za[1][ao];
  }

  f32x4 acc[4][4];
#pragma unroll
  for (int i = 0; i < 4; ++i)
#pragma unroll
    for (int j = 0; j < 4; ++j) acc[i][j] = (f32x4){0.f, 0.f, 0.f, 0.f};

#pragma unroll
  for (int mi = 0; mi < 4; ++mi)
#pragma unroll
    for (int nj = 0; nj < 4; ++nj) {
      acc[mi][nj] = __builtin_amdgcn_mfma_f32_16x16x32_bf16(ah[mi], bh[nj],
                                                            acc[mi][nj], 0, 0, 0);
      acc[mi][nj] = __builtin_amdgcn_mfma_f32_16x16x32_bf16(ah[mi], bl[nj],
                                                            acc[mi][nj], 0, 0, 0);
      acc[mi][nj] = __builtin_amdgcn_mfma_f32_16x16x32_bf16(al[mi], bh[nj],
                                                            acc[mi][nj], 0, 0, 0);
    }

  const int crow = (lane >> 4) * 4;
#pragma unroll
  for (int nj = 0; nj < 4; ++nj) {
    const int col = n0 + wn * 64 + nj * 16 + r15;
    const float bias = b1d[col];
#pragma unroll
    for (int mi = 0; mi < 4; ++mi) {
      const int rb = row0 + wm * 64 + mi * 16 + crow;
#pragma unroll
      for (int r = 0; r < 4; ++r) {
        float v = leaky(acc[mi][nj][r] + bias);
        unsigned short hi = f2bf(v);
        unsigned short lo = f2bf(v - bf2f(hi));
        const size_t o = (size_t)(rb + r) * HID + col;
        H1h[o] = (short)hi;
        H1l[o] = (short)lo;
      }
    }
  }
}

// ---------------------------------------------------------------------------
// Mid (MFMA): H2 = leaky(H1 @ W2 + b2), split-bf16 3-product.
// NEW: 128x128 tile, BK=32, 4 waves (2M x 2N), 64KB LDS -> 2 blocks/CU
// (cross-block overlap hides barrier drain). Same R4 inner structure.
// Per buffer: A 16KB @0 | B 16KB @16384; dbuf @32768.
// grid 1024 blocks (128 mb x 8 nb), XCD-chunked swizzle.
// ---------------------------------------------------------------------------
__global__ __launch_bounds__(256, 2) void k_mid(
    const short* __restrict__ H1h, const short* __restrict__ H1l,
    const short* __restrict__ W2Th, const short* __restrict__ W2Tl,
    const float* __restrict__ b2d, short* __restrict__ H2h,
    short* __restrict__ H2l) {
  __shared__ char lds[65536];

  const int tid = threadIdx.x;
  const int lane = tid & 63;
  const int wave = tid >> 6;  // 0..3

  const int bid = blockIdx.x;
  const int wg = (bid & 7) * 128 + (bid >> 3);  // 1024 blocks, 8 XCD chunks
  const int mb = wg >> 3, nb = wg & 7;
  const int row0 = mb * 128;
  const int n0 = nb * 128;
  const int wm = wave >> 1;   // 0..1 (64-row half)
  const int wnb = wave & 1;   // 0..1 (64-col half)
  const int r15 = lane & 15;
  const int kq = lane >> 4;
  const int l7 = lane & 7;
  const int l3 = lane >> 3;

  // staging: 16 A-chunks (waves 0,1) + 16 B-chunks (waves 2,3); 8 per wave.
  const char* srcB[8];
  {
    const int s = l7 ^ l3;
    const char* hsrc;
    const char* lsrc;
    int rbase;
    if (wave < 2) {
      hsrc = (const char*)H1h;
      lsrc = (const char*)H1l;
      rbase = row0;
    } else {
      hsrc = (const char*)W2Th;
      lsrc = (const char*)W2Tl;
      rbase = n0;
    }
    const char* base = (s < 4) ? hsrc : lsrc;
    const int w2 = wave & 1;  // chunk group within operand
#pragma unroll
    for (int i = 0; i < 8; ++i) {
      const int c = w2 * 8 + i;  // 0..15
      const int rloc = c * 8 + l3;
      srcB[i] = base + (size_t)(rbase + rloc) * 2048 + (size_t)(s & 3) * 16;
    }
  }
  const int dchunk0 = (wave < 2) ? (wave & 1) * 8192 : 16384 + (wave & 1) * 8192;

  // fragment read offsets (phys slot = log ^ (row&7); row&7 == l7)
  const int offA0 = (wm * 64 + r15) * 128 + ((0 + kq) ^ l7) * 16;
  const int offA1 = (wm * 64 + r15) * 128 + ((4 + kq) ^ l7) * 16;
  const int offB0 = 16384 + (wnb * 64 + r15) * 128 + ((0 + kq) ^ l7) * 16;
  const int offB1 = 16384 + (wnb * 64 + r15) * 128 + ((4 + kq) ^ l7) * 16;

  f32x4 acc[4][4];
#pragma unroll
  for (int i = 0; i < 4; ++i)
#pragma unroll
    for (int j = 0; j < 4; ++j) acc[i][j] = (f32x4){0.f, 0.f, 0.f, 0.f};

#define STAGE(buf, kb)                                                   \
  {                                                                      \
    _Pragma("unroll") for (int i = 0; i < 8; ++i) {                      \
      GLD_LDS16(srcB[i] + (kb), &lds[(buf)*32768 + dchunk0 + i * 1024]); \
    }                                                                    \
  }

  STAGE(0, 0);
  __syncthreads();

  int cur = 0;
  for (int t = 0; t < 32; ++t) {
    if (t < 31) STAGE(cur ^ 1, (t + 1) * 64);

    const char* buf = &lds[cur * 32768];
    bf16x8 bh[4], bl[4];
#pragma unroll
    for (int nj = 0; nj < 4; ++nj) {
      bh[nj] = *(const bf16x8*)(buf + offB0 + nj * 2048);
      bl[nj] = *(const bf16x8*)(buf + offB1 + nj * 2048);
    }
#pragma unroll
    for (int mi = 0; mi < 4; ++mi) {
      bf16x8 ah = *(const bf16x8*)(buf + offA0 + mi * 2048);
      bf16x8 al = *(const bf16x8*)(buf + offA1 + mi * 2048);
#pragma unroll
      for (int nj = 0; nj < 4; ++nj) {
        acc[mi][nj] =
            __builtin_amdgcn_mfma_f32_16x16x32_bf16(ah, bh[nj], acc[mi][nj], 0, 0, 0);
        acc[mi][nj] =
            __builtin_amdgcn_mfma_f32_16x16x32_bf16(ah, bl[nj], acc[mi][nj], 0, 0, 0);
        acc[mi][nj] =
            __builtin_amdgcn_mfma_f32_16x16x32_bf16(al, bh[nj], acc[mi][nj], 0, 0, 0);
      }
    }
    __syncthreads();
    cur ^= 1;
  }
#undef STAGE

  const int crow = (lane >> 4) * 4;
#pragma unroll
  for (int nj = 0; nj < 4; ++nj) {
    const int col = n0 + wnb * 64 + nj * 16 + r15;
    const float bv = b2d[col];
#pragma unroll
    for (int mi = 0; mi < 4; ++mi) {
      const int rb = row0 + wm * 64 + mi * 16 + crow;
#pragma unroll
      for (int r = 0; r < 4; ++r) {
        float v = leaky(acc[mi][nj][r] + bv);
        unsigned short hi = f2bf(v);
        unsigned short lo = f2bf(v - bf2f(hi));
        const size_t o = (size_t)(rb + r) * HID + col;
        H2h[o] = (short)hi;
        H2l[o] = (short)lo;
      }
    }
  }
}

// ---------------------------------------------------------------------------
// Fused Layer3 + next-stage Layer1, per 32-row slice. [R10 verbatim]
// ---------------------------------------------------------------------------
__global__ __launch_bounds__(256, 2) void k_l3l1(
    const short* __restrict__ H2h, const short* __restrict__ H2l,
    const short* __restrict__ W3Th, const short* __restrict__ W3Tl,
    const float* __restrict__ b3d, float* __restrict__ kout,
    const float* __restrict__ K0, const float* __restrict__ K1,
    const float* __restrict__ K2, const float* __restrict__ K3,
    const float* __restrict__ K4, float* __restrict__ y, int combine,
    float p1, float p2, float p3, float p4, float p5, float pc, float hb1,
    float hb2, float hb3, float hb4, float hb5, float hb6,
    const short* __restrict__ W1Tnh, const short* __restrict__ W1Tnl,
    const float* __restrict__ b1n, short* __restrict__ H1h,
    short* __restrict__ H1l) {
  __shared__ short lds[2][4096];
  __shared__ short zs[2][32][40];

  const int tid = threadIdx.x, lane = tid & 63, wave = tid >> 6;
  const int row0 = blockIdx.x * 32;
  const int wm = wave & 1, wn = wave >> 1;

  const int half = tid >> 7;
  const int idx = tid & 127;
  const int srow = idx >> 2;
  const int sd = idx & 3;
  const int slog = sd ^ ((srow >> 1) & 3);
  const short* Asrc = half ? H2l : H2h;
  const short* Bsrc = half ? W3Tl : W3Th;
  const char* aSrc = (const char*)(Asrc + (size_t)(row0 + srow) * HID) + slog * 16;
  const char* bSrc = (const char*)(Bsrc + (size_t)srow * HID) + slog * 16;
  short* aDst0 = &lds[0][half * 1024 + idx * 8];
  short* bDst0 = &lds[0][2048 + half * 1024 + idx * 8];
  short* aDst1 = &lds[1][half * 1024 + idx * 8];
  short* bDst1 = &lds[1][2048 + half * 1024 + idx * 8];

  const int r15 = lane & 15;
  const int kc = lane >> 4;
  const int aRow = wm * 16 + r15;
  const int bRow = wn * 16 + r15;
  const int aOff = aRow * 32 + (kc ^ ((aRow >> 1) & 3)) * 8;
  const int bOff = 2048 + bRow * 32 + (kc ^ ((bRow >> 1) & 3)) * 8;

  f32x4 acc = (f32x4){0.f, 0.f, 0.f, 0.f};

#define STAGE3(ad, bd, kb)          \
  {                                 \
    GLD_LDS16(aSrc + (kb), (ad));   \
    GLD_LDS16(bSrc + (kb), (bd));   \
  }

  STAGE3(aDst0, bDst0, 0);
  __syncthreads();

  for (int t = 0; t < 32; ++t) {
    const int cur = t & 1;
    if (t < 31) {
      if (cur == 0) STAGE3(aDst1, bDst1, (t + 1) * 64)
      else STAGE3(aDst0, bDst0, (t + 1) * 64)
    }
    const short* buf = lds[cur];
    bf16x8 ah = *(const bf16x8*)(buf + aOff);
    bf16x8 al = *(const bf16x8*)(buf + 1024 + aOff);
    bf16x8 bh = *(const bf16x8*)(buf + bOff);
    bf16x8 bl = *(const bf16x8*)(buf + 1024 + bOff);
    acc = __builtin_amdgcn_mfma_f32_16x16x32_bf16(ah, bh, acc, 0, 0, 0);
    acc = __builtin_amdgcn_mfma_f32_16x16x32_bf16(ah, bl, acc, 0, 0, 0);
    acc = __builtin_amdgcn_mfma_f32_16x16x32_bf16(al, bh, acc, 0, 0, 0);
    __syncthreads();
  }
#undef STAGE3

  {
    const int c = wn * 16 + r15;
    const int rb = wm * 16 + (lane >> 4) * 4;
    const float bias = (c < LOOK) ? b3d[c] : 0.f;
#pragma unroll
    for (int r = 0; r < 4; ++r) {
      const int rloc = rb + r;
      const int row = row0 + rloc;
      const float kv = acc[r] + bias;
      float zv = 0.f;
      if (c < LOOK) {
        const size_t id = (size_t)row * LOOK + c;
        const float yv = y[id];
        if (combine) {
          float yn = yv + hb1 * K0[id] + hb2 * K1[id] + hb3 * K2[id] +
                     hb4 * K3[id] + hb5 * K4[id] + hb6 * kv;
          y[id] = yn;
          zv = yn;
        } else {
          kout[id] = kv;
          zv = yv + pc * kv;
          if (p1 != 0.f) zv += p1 * K0[id];
          if (p2 != 0.f) zv += p2 * K1[id];
          if (p3 != 0.f) zv += p3 * K2[id];
          if (p4 != 0.f) zv += p4 * K3[id];
          if (p5 != 0.f) zv += p5 * K4[id];
        }
      }
      unsigned short hi = f2bf(zv);
      unsigned short lo = f2bf(zv - bf2f(hi));
      zs[0][rloc][c] = (short)hi;
      zs[1][rloc][c] = (short)lo;
    }
  }
  __syncthreads();

  bf16x8 zfh[2], zfl[2];
#pragma unroll
  for (int mi = 0; mi < 2; ++mi) {
    zfh[mi] = *(const bf16x8*)&zs[0][mi * 16 + r15][kc * 8];
    zfl[mi] = *(const bf16x8*)&zs[1][mi * 16 + r15][kc * 8];
  }
  const int crow = (lane >> 4) * 4;
#pragma unroll
  for (int nj = 0; nj < 16; ++nj) {
    const int col = wave * 256 + nj * 16 + r15;
    const size_t bo = (size_t)col * 32 + kc * 8;
    bf16x8 bh = *(const bf16x8*)&W1Tnh[bo];
    bf16x8 bl = *(const bf16x8*)&W1Tnl[bo];
    f32x4 a0 = (f32x4){0.f, 0.f, 0.f, 0.f};
    f32x4 a1 = (f32x4){0.f, 0.f, 0.f, 0.f};
    a0 = __builtin_amdgcn_mfma_f32_16x16x32_bf16(zfh[0], bh, a0, 0, 0, 0);
    a0 = __builtin_amdgcn_mfma_f32_16x16x32_bf16(zfh[0], bl, a0, 0, 0, 0);
    a0 = __builtin_amdgcn_mfma_f32_16x16x32_bf16(zfl[0], bh, a0, 0, 0, 0);
    a1 = __builtin_amdgcn_mfma_f32_16x16x32_bf16(zfh[1], bh, a1, 0, 0, 0);
    a1 = __builtin_amdgcn_mfma_f32_16x16x32_bf16(zfh[1], bl, a1, 0, 0, 0);
    a1 = __builtin_amdgcn_mfma_f32_16x16x32_bf16(zfl[1], bh, a1, 0, 0, 0);
    const float bias = b1n[col];
#pragma unroll
    for (int mi = 0; mi < 2; ++mi) {
      const f32x4 av = mi ? a1 : a0;
      const int rbase = row0 + mi * 16 + crow;
#pragma unroll
      for (int r = 0; r < 4; ++r) {
        float v = leaky(av[r] + bias);
        unsigned short hi = f2bf(v);
        unsigned short lo = f2bf(v - bf2f(hi));
        const size_t o = (size_t)(rbase + r) * HID + col;
        H1h[o] = (short)hi;
        H1l[o] = (short)lo;
      }
    }
  }
}

// ---------------------------------------------------------------------------
__global__ __launch_bounds__(256) void k_readout(const float* __restrict__ y,
                                                 const float* __restrict__ Wf,
                                                 const float* __restrict__ bf,
                                                 float* __restrict__ out) {
  const int r = blockIdx.x * blockDim.x + threadIdx.x;
  if (r >= BATCH) return;
  float acc = bf[0];
#pragma unroll
  for (int c = 0; c < LOOK; ++c) acc += y[(size_t)r * LOOK + c] * Wf[c];
  out[r] = acc;
}

// ---------------------------------------------------------------------------
extern "C" void kernel_launch(void* const* d_in, const int* in_sizes, int n_in,
                              void* d_out, int out_size, void* d_ws,
                              size_t ws_size, hipStream_t stream) {
  const float* y0 = (const float*)d_in[0];
  const float* W1 = (const float*)d_in[1];
  const float* b1 = (const float*)d_in[2];
  const float* W2 = (const float*)d_in[3];
  const float* b2 = (const float*)d_in[4];
  const float* W3 = (const float*)d_in[5];
  const float* b3 = (const float*)d_in[6];
  const float* Wf = (const float*)d_in[7];
  const float* bf = (const float*)d_in[8];
  float* out = (float*)d_out;

  const size_t NY = (size_t)BATCH * LOOK;
  float* f = (float*)d_ws;
  float* y = f;
  float* kk[5];
  for (int i = 0; i < 5; ++i) kk[i] = f + NY * (1 + i);
  char* p = (char*)(f + NY * 6);
  short* zh = (short*)p; p += (size_t)BATCH * 32 * 2;
  short* zl = (short*)p; p += (size_t)BATCH * 32 * 2;
  short* H1h = (short*)p; p += (size_t)BATCH * HID * 2;
  short* H1l = (short*)p; p += (size_t)BATCH * HID * 2;
  short* H2h = (short*)p; p += (size_t)BATCH * HID * 2;
  short* H2l = (short*)p; p += (size_t)BATCH * HID * 2;
  short* W2Th = (short*)p; p += (size_t)HID * HID * 2;
  short* W2Tl = (short*)p; p += (size_t)HID * HID * 2;
  short* W1Th = (short*)p; p += (size_t)DEPTH * HID * 32 * 2;
  short* W1Tl = (short*)p; p += (size_t)DEPTH * HID * 32 * 2;
  short* W3Th = (short*)p; p += (size_t)32 * HID * 2;
  short* W3Tl = (short*)p;

  hipMemcpyAsync(y, y0, NY * sizeof(float), hipMemcpyDeviceToDevice, stream);

  k_w1t_all<<<dim3(DEPTH * 1024 * 32 / 256), 256, 0, stream>>>(W1, W1Th, W1Tl);
  k_zinit<<<dim3(BATCH * 32 / 256), 256, 0, stream>>>(y0, zh, zl);
  k_l1<<<dim3(BATCH / 128, HID / 256), 512, 0, stream>>>(zh, zl, W1Th, W1Tl,
                                                         b1, H1h, H1l);

  const double hh = 1.0 / 16.0;
  static const double A[6][5] = {
      {0, 0, 0, 0, 0},
      {1.0 / 5, 0, 0, 0, 0},
      {3.0 / 40, 9.0 / 40, 0, 0, 0},
      {44.0 / 45, -56.0 / 15, 32.0 / 9, 0, 0},
      {19372.0 / 6561, -25360.0 / 2187, 64448.0 / 6561, -212.0 / 729, 0},
      {9017.0 / 3168, -355.0 / 33, 46732.0 / 5247, 49.0 / 176,
       -5103.0 / 18656},
  };
  static const double Bb[6] = {35.0 / 384,  0,              500.0 / 1113,
                               125.0 / 192, -2187.0 / 6784, 11.0 / 84};

  const float hb1 = (float)(hh * Bb[0]);
  const float hb2 = (float)(hh * Bb[1]);
  const float hb3 = (float)(hh * Bb[2]);
  const float hb4 = (float)(hh * Bb[3]);
  const float hb5 = (float)(hh * Bb[4]);
  const float hb6 = (float)(hh * Bb[5]);

  for (int d = 0; d < DEPTH; ++d) {
    const float* W2d = W2 + (size_t)d * HID * HID;
    const float* b2d = b2 + (size_t)d * HID;
    const float* W3d = W3 + (size_t)d * HID * LOOK;
    const float* b3d = b3 + (size_t)d * LOOK;

    k_w2split<<<dim3(16, 16), 256, 0, stream>>>(W2d, W2Th, W2Tl);
    k_w3t<<<dim3(128), 256, 0, stream>>>(W3d, W3Th, W3Tl);

    for (int s = 0; s < NSTEPS; ++s) {
      for (int st = 0; st < 6; ++st) {
        float pv[5] = {0.f, 0.f, 0.f, 0.f, 0.f};
        float pc = 0.f;
        if (st < 5) {
          for (int jj = 0; jj < 5; ++jj)
            if (jj < st) pv[jj] = (float)(hh * A[st + 1][jj]);
          pc = (float)(hh * A[st + 1][st]);
        }
        int dn = d;
        if (st == 5 && s == NSTEPS - 1) dn = (d + 1 < DEPTH) ? d + 1 : d;
        const short* W1Tnh = W1Th + (size_t)dn * HID * 32;
        const short* W1Tnl = W1Tl + (size_t)dn * HID * 32;
        const float* b1n = b1 + (size_t)dn * HID;

        k_mid<<<dim3(1024), 256, 0, stream>>>(H1h, H1l, W2Th, W2Tl, b2d, H2h,
                                              H2l);
        const int comb = (st == 5) ? 1 : 0;
        float* kout = (st < 5) ? kk[st] : kk[0];
        k_l3l1<<<dim3(BATCH / 32), 256, 0, stream>>>(
            H2h, H2l, W3Th, W3Tl, b3d, kout, kk[0], kk[1], kk[2], kk[3],
            kk[4], y, comb, pv[0], pv[1], pv[2], pv[3], pv[4], pc, hb1, hb2,
            hb3, hb4, hb5, hb6, W1Tnh, W1Tnl, b1n, H1h, H1l);
      }
    }
  }

  k_readout<<<dim3(BATCH / 256), 256, 0, stream>>>(y, Wf, bf, out);
}

// Round 12
// 114793.115 us; speedup vs baseline: 1.4249x; 1.1383x over previous
//
#include <hip/hip_runtime.h>

#define BATCH 16384
#define LOOK 30
#define HID 1024
#define DEPTH 10
#define NSTEPS 16
#define ALPHA 0.3f

typedef short bf16x8 __attribute__((ext_vector_type(8)));
typedef float f32x4 __attribute__((ext_vector_type(4)));

__device__ __forceinline__ float leaky(float x) { return x > 0.f ? x : ALPHA * x; }

__device__ __forceinline__ unsigned short f2bf(float x) {
  unsigned u = __builtin_bit_cast(unsigned, x);
  unsigned r = u + 0x7FFFu + ((u >> 16) & 1u);
  return (unsigned short)(r >> 16);
}
__device__ __forceinline__ float bf2f(unsigned short b) {
  return __builtin_bit_cast(float, (unsigned)b << 16);
}

#define GLD_LDS16(g, l)                                        \
  __builtin_amdgcn_global_load_lds(                            \
      (const __attribute__((address_space(1))) void*)(g),      \
      (__attribute__((address_space(3))) void*)(l), 16, 0, 0)

// ---------------------------------------------------------------------------
// Prep: W2[k][n] -> W2T[n][k] hi/lo bf16. grid (16,16), 256 thr.
// ---------------------------------------------------------------------------
__global__ __launch_bounds__(256) void k_w2split(const float* __restrict__ W2d,
                                                 short* __restrict__ W2Th,
                                                 short* __restrict__ W2Tl) {
  __shared__ float t[64][65];
  const int kb = blockIdx.x * 64;
  const int nb = blockIdx.y * 64;
  for (int i = threadIdx.x; i < 4096; i += 256) {
    int r = i >> 6, c = i & 63;
    t[r][c] = W2d[(size_t)(kb + r) * HID + nb + c];
  }
  __syncthreads();
  for (int i = threadIdx.x; i < 4096; i += 256) {
    int r = i >> 6, c = i & 63;
    float v = t[c][r];
    unsigned short hi = f2bf(v);
    unsigned short lo = f2bf(v - bf2f(hi));
    W2Th[(size_t)(nb + r) * HID + kb + c] = (short)hi;
    W2Tl[(size_t)(nb + r) * HID + kb + c] = (short)lo;
  }
}

// Prep (ALL depths): W1[d][30][1024] -> W1T[d][1024 n][32 k] hi/lo. grid 1280.
__global__ __launch_bounds__(256) void k_w1t_all(const float* __restrict__ W1,
                                                 short* __restrict__ W1Th,
                                                 short* __restrict__ W1Tl) {
  const int idx = blockIdx.x * 256 + threadIdx.x;
  if (idx >= DEPTH * 1024 * 32) return;
  const int d = idx >> 15;
  const int rem = idx & 32767;
  const int n = rem >> 5, k = rem & 31;
  float v = (k < LOOK) ? W1[(size_t)d * LOOK * HID + (size_t)k * HID + n] : 0.f;
  unsigned short hi = f2bf(v);
  unsigned short lo = f2bf(v - bf2f(hi));
  W1Th[idx] = (short)hi;
  W1Tl[idx] = (short)lo;
}

// Prep: W3[1024][30] -> W3T[32 n][1024 k] hi/lo (n 30,31 zero). grid 128.
__global__ __launch_bounds__(256) void k_w3t(const float* __restrict__ W3d,
                                             short* __restrict__ W3Th,
                                             short* __restrict__ W3Tl) {
  const int idx = blockIdx.x * 256 + threadIdx.x;
  if (idx >= 32 * 1024) return;
  const int n = idx >> 10, k = idx & 1023;
  float v = (n < LOOK) ? W3d[(size_t)k * LOOK + n] : 0.f;
  unsigned short hi = f2bf(v);
  unsigned short lo = f2bf(v - bf2f(hi));
  W3Th[idx] = (short)hi;
  W3Tl[idx] = (short)lo;
}

// Init: z = y0 (padded to 32 cols) hi/lo. grid 2048.
__global__ __launch_bounds__(256) void k_zinit(const float* __restrict__ y0,
                                               short* __restrict__ zh,
                                               short* __restrict__ zl) {
  const int idx = blockIdx.x * 256 + threadIdx.x;
  if (idx >= BATCH * 32) return;
  const int r = idx >> 5, c = idx & 31;
  float v = (c < LOOK) ? y0[(size_t)r * LOOK + c] : 0.f;
  unsigned short hi = f2bf(v);
  unsigned short lo = f2bf(v - bf2f(hi));
  zh[idx] = (short)hi;
  zl[idx] = (short)lo;
}

// ---------------------------------------------------------------------------
// Layer1 standalone (first eval only): H1 = leaky(z @ W1 + b1). [R4 verbatim]
// ---------------------------------------------------------------------------
__global__ __launch_bounds__(512, 2) void k_l1(
    const short* __restrict__ zh, const short* __restrict__ zl,
    const short* __restrict__ W1Th, const short* __restrict__ W1Tl,
    const float* __restrict__ b1d, short* __restrict__ H1h,
    short* __restrict__ H1l) {
  __shared__ short za[2][128 * 32];
  const int tid = threadIdx.x, lane = tid & 63, wave = tid >> 6;
  const int row0 = blockIdx.x * 128;
  const int n0 = blockIdx.y * 256;
  const int wm = wave >> 2, wn = wave & 3;
  const int r15 = lane & 15;
  const int bk = (lane >> 4) * 8;

  bf16x8 bh[4], bl[4];
#pragma unroll
  for (int nj = 0; nj < 4; ++nj) {
    const size_t bo = (size_t)(n0 + wn * 64 + nj * 16 + r15) * 32 + bk;
    bh[nj] = *(const bf16x8*)&W1Th[bo];
    bl[nj] = *(const bf16x8*)&W1Tl[bo];
  }

  GLD_LDS16((const char*)(zh + (size_t)row0 * 32) + tid * 16, &za[0][tid * 8]);
  GLD_LDS16((const char*)(zl + (size_t)row0 * 32) + tid * 16, &za[1][tid * 8]);
  __syncthreads();

  bf16x8 ah[4], al[4];
#pragma unroll
  for (int mi = 0; mi < 4; ++mi) {
    const int ao = (wm * 64 + mi * 16 + r15) * 32 + bk;
    ah[mi] = *(const bf16x8*)&za[0][ao];
    al[mi] = *(const bf16x8*)&za[1][ao];
  }

  f32x4 acc[4][4];
#pragma unroll
  for (int i = 0; i < 4; ++i)
#pragma unroll
    for (int j = 0; j < 4; ++j) acc[i][j] = (f32x4){0.f, 0.f, 0.f, 0.f};

#pragma unroll
  for (int mi = 0; mi < 4; ++mi)
#pragma unroll
    for (int nj = 0; nj < 4; ++nj) {
      acc[mi][nj] = __builtin_amdgcn_mfma_f32_16x16x32_bf16(ah[mi], bh[nj],
                                                            acc[mi][nj], 0, 0, 0);
      acc[mi][nj] = __builtin_amdgcn_mfma_f32_16x16x32_bf16(ah[mi], bl[nj],
                                                            acc[mi][nj], 0, 0, 0);
      acc[mi][nj] = __builtin_amdgcn_mfma_f32_16x16x32_bf16(al[mi], bh[nj],
                                                            acc[mi][nj], 0, 0, 0);
    }

  const int crow = (lane >> 4) * 4;
#pragma unroll
  for (int nj = 0; nj < 4; ++nj) {
    const int col = n0 + wn * 64 + nj * 16 + r15;
    const float bias = b1d[col];
#pragma unroll
    for (int mi = 0; mi < 4; ++mi) {
      const int rb = row0 + wm * 64 + mi * 16 + crow;
#pragma unroll
      for (int r = 0; r < 4; ++r) {
        float v = leaky(acc[mi][nj][r] + bias);
        unsigned short hi = f2bf(v);
        unsigned short lo = f2bf(v - bf2f(hi));
        const size_t o = (size_t)(rb + r) * HID + col;
        H1h[o] = (short)hi;
        H1l[o] = (short)lo;
      }
    }
  }
}

// ---------------------------------------------------------------------------
// Mid (MFMA): 128x128 tile, BK=32, 4 waves, 64KB LDS, 2 blocks/CU. [R11 loop]
// NEW epilogue: h2 = leaky(acc+b2) stays on-chip; transposed through LDS
// (subtile layout [row>>2][k>>4][(row&3)^((row>>2)&3)][k&15]) and multiplied
// by the W3T k-slice -> kpart[nb][row][32] fp32 partials. H2 never hits HBM.
// grid 1024 blocks (128 mb x 8 nb), XCD-chunked swizzle.
// ---------------------------------------------------------------------------
__global__ __launch_bounds__(256, 2) void k_mid(
    const short* __restrict__ H1h, const short* __restrict__ H1l,
    const short* __restrict__ W2Th, const short* __restrict__ W2Tl,
    const float* __restrict__ b2d, const short* __restrict__ W3Th,
    const short* __restrict__ W3Tl, float* __restrict__ kpart) {
  __shared__ char lds[65536];

  const int tid = threadIdx.x;
  const int lane = tid & 63;
  const int wave = tid >> 6;  // 0..3

  const int bid = blockIdx.x;
  const int wg = (bid & 7) * 128 + (bid >> 3);
  const int mb = wg >> 3, nb = wg & 7;
  const int row0 = mb * 128;
  const int n0 = nb * 128;
  const int wm = wave >> 1;
  const int wnb = wave & 1;
  const int r15 = lane & 15;
  const int kq = lane >> 4;
  const int l7 = lane & 7;
  const int l3 = lane >> 3;

  const char* srcB[8];
  {
    const int s = l7 ^ l3;
    const char* hsrc;
    const char* lsrc;
    int rbase;
    if (wave < 2) {
      hsrc = (const char*)H1h;
      lsrc = (const char*)H1l;
      rbase = row0;
    } else {
      hsrc = (const char*)W2Th;
      lsrc = (const char*)W2Tl;
      rbase = n0;
    }
    const char* base = (s < 4) ? hsrc : lsrc;
    const int w2 = wave & 1;
#pragma unroll
    for (int i = 0; i < 8; ++i) {
      const int c = w2 * 8 + i;
      const int rloc = c * 8 + l3;
      srcB[i] = base + (size_t)(rbase + rloc) * 2048 + (size_t)(s & 3) * 16;
    }
  }
  const int dchunk0 = (wave < 2) ? (wave & 1) * 8192 : 16384 + (wave & 1) * 8192;

  const int offA0 = (wm * 64 + r15) * 128 + ((0 + kq) ^ l7) * 16;
  const int offA1 = (wm * 64 + r15) * 128 + ((4 + kq) ^ l7) * 16;
  const int offB0 = 16384 + (wnb * 64 + r15) * 128 + ((0 + kq) ^ l7) * 16;
  const int offB1 = 16384 + (wnb * 64 + r15) * 128 + ((4 + kq) ^ l7) * 16;

  f32x4 acc[4][4];
#pragma unroll
  for (int i = 0; i < 4; ++i)
#pragma unroll
    for (int j = 0; j < 4; ++j) acc[i][j] = (f32x4){0.f, 0.f, 0.f, 0.f};

#define STAGE(buf, kb)                                                   \
  {                                                                      \
    _Pragma("unroll") for (int i = 0; i < 8; ++i) {                      \
      GLD_LDS16(srcB[i] + (kb), &lds[(buf)*32768 + dchunk0 + i * 1024]); \
    }                                                                    \
  }

  STAGE(0, 0);
  __syncthreads();

  int cur = 0;
  for (int t = 0; t < 32; ++t) {
    if (t < 31) STAGE(cur ^ 1, (t + 1) * 64);

    const char* buf = &lds[cur * 32768];
    bf16x8 bh[4], bl[4];
#pragma unroll
    for (int nj = 0; nj < 4; ++nj) {
      bh[nj] = *(const bf16x8*)(buf + offB0 + nj * 2048);
      bl[nj] = *(const bf16x8*)(buf + offB1 + nj * 2048);
    }
#pragma unroll
    for (int mi = 0; mi < 4; ++mi) {
      bf16x8 ah = *(const bf16x8*)(buf + offA0 + mi * 2048);
      bf16x8 al = *(const bf16x8*)(buf + offA1 + mi * 2048);
#pragma unroll
      for (int nj = 0; nj < 4; ++nj) {
        acc[mi][nj] =
            __builtin_amdgcn_mfma_f32_16x16x32_bf16(ah, bh[nj], acc[mi][nj], 0, 0, 0);
        acc[mi][nj] =
            __builtin_amdgcn_mfma_f32_16x16x32_bf16(ah, bl[nj], acc[mi][nj], 0, 0, 0);
        acc[mi][nj] =
            __builtin_amdgcn_mfma_f32_16x16x32_bf16(al, bh[nj], acc[mi][nj], 0, 0, 0);
      }
    }
    __syncthreads();
    cur ^= 1;
  }
#undef STAGE

  // ===== epilogue: kpart[nb] partial of kout via on-chip transpose =====
  // write h2 (split hi/lo) into transpose layout (hi @0, lo @32768)
#pragma unroll
  for (int nj = 0; nj < 4; ++nj) {
    const int k = wnb * 64 + nj * 16 + r15;  // local k (= h2 col)
    const float bv = b2d[n0 + k];
    const int ksub = k >> 4;
    const int klo = (k & 15) * 2;
#pragma unroll
    for (int mi = 0; mi < 4; ++mi) {
      const int rowq = wm * 16 + mi * 4 + kq;  // row>>2
      const int xr = kq & 3;                   // (row>>2)&3
      const int base = (rowq * 8 + ksub) * 128 + klo;
#pragma unroll
      for (int r = 0; r < 4; ++r) {
        float v = leaky(acc[mi][nj][r] + bv);
        unsigned short hi = f2bf(v);
        unsigned short lo = f2bf(v - bf2f(hi));
        const int off = base + ((r ^ xr) & 3) * 32;
        *(short*)(lds + off) = (short)hi;
        *(short*)(lds + 32768 + off) = (short)lo;
      }
    }
  }
  __syncthreads();

  // small GEMM: rows (wave*32..+31) x N=32 x K=128, split-bf16 3-product
  {
    const int kq8 = kq * 8;
    f32x4 kacc[2][2];
#pragma unroll
    for (int i = 0; i < 2; ++i)
#pragma unroll
      for (int j = 0; j < 2; ++j) kacc[i][j] = (f32x4){0.f, 0.f, 0.f, 0.f};

#pragma unroll
    for (int kt = 0; kt < 4; ++kt) {
      bf16x8 ah[2], al[2];
#pragma unroll
      for (int mii = 0; mii < 2; ++mii) {
        const int row = wave * 32 + mii * 16 + r15;
        const int rowq = row >> 2;
        const int kk = kt * 32 + kq8;
        const int byteA = (rowq * 8 + (kk >> 4)) * 128 +
                          (((row & 3) ^ (rowq & 3)) & 3) * 32 + (kk & 15) * 2;
        ah[mii] = *(const bf16x8*)(lds + byteA);
        al[mii] = *(const bf16x8*)(lds + 32768 + byteA);
      }
#pragma unroll
      for (int njj = 0; njj < 2; ++njj) {
        const int col = njj * 16 + r15;
        const size_t wo = (size_t)col * 1024 + n0 + kt * 32 + kq8;
        bf16x8 wh = *(const bf16x8*)&W3Th[wo];
        bf16x8 wl = *(const bf16x8*)&W3Tl[wo];
#pragma unroll
        for (int mii = 0; mii < 2; ++mii) {
          kacc[mii][njj] = __builtin_amdgcn_mfma_f32_16x16x32_bf16(
              ah[mii], wh, kacc[mii][njj], 0, 0, 0);
          kacc[mii][njj] = __builtin_amdgcn_mfma_f32_16x16x32_bf16(
              ah[mii], wl, kacc[mii][njj], 0, 0, 0);
          kacc[mii][njj] = __builtin_amdgcn_mfma_f32_16x16x32_bf16(
              al[mii], wh, kacc[mii][njj], 0, 0, 0);
        }
      }
    }

    const int crow2 = kq * 4;
#pragma unroll
    for (int njj = 0; njj < 2; ++njj) {
      const int col = njj * 16 + r15;
#pragma unroll
      for (int mii = 0; mii < 2; ++mii) {
        const int rbase = row0 + wave * 32 + mii * 16 + crow2;
#pragma unroll
        for (int r = 0; r < 4; ++r) {
          kpart[(size_t)nb * ((size_t)BATCH * 32) + (size_t)(rbase + r) * 32 +
                col] = kacc[mii][njj][r];
        }
      }
    }
  }
}

// ---------------------------------------------------------------------------
// Fused combine + next-stage Layer1, per 32-row slice. grid 512, 256 thr.
// Part 1 (NEW): kv = b3 + sum_nb kpart[nb][row][c]; DoPri combine; z -> LDS.
// Part 2: H1(next) = leaky(z @ W1next + b1next). [R10 verbatim]
// ---------------------------------------------------------------------------
__global__ __launch_bounds__(256, 4) void k_l3l1(
    const float* __restrict__ kpart, const float* __restrict__ b3d,
    float* __restrict__ kout, const float* __restrict__ K0,
    const float* __restrict__ K1, const float* __restrict__ K2,
    const float* __restrict__ K3, const float* __restrict__ K4,
    float* __restrict__ y, int combine, float p1, float p2, float p3,
    float p4, float p5, float pc, float hb1, float hb2, float hb3, float hb4,
    float hb5, float hb6, const short* __restrict__ W1Tnh,
    const short* __restrict__ W1Tnl, const float* __restrict__ b1n,
    short* __restrict__ H1h, short* __restrict__ H1l) {
  __shared__ short zs[2][32][40];

  const int tid = threadIdx.x, lane = tid & 63, wave = tid >> 6;
  const int row0 = blockIdx.x * 32;
  const int wm = wave & 1, wn = wave >> 1;
  const int r15 = lane & 15;
  const int kc = lane >> 4;

  // ---- Part 1: kv from kpart partials; combine; z into LDS
  {
    const int c = wn * 16 + r15;
    const int rb = wm * 16 + kc * 4;
    const float bias = (c < LOOK) ? b3d[c] : 0.f;
#pragma unroll
    for (int r = 0; r < 4; ++r) {
      const int rloc = rb + r;
      const int row = row0 + rloc;
      float zv = 0.f;
      if (c < LOOK) {
        float kv = bias;
#pragma unroll
        for (int nbi = 0; nbi < 8; ++nbi)
          kv += kpart[(size_t)nbi * ((size_t)BATCH * 32) + (size_t)row * 32 + c];
        const size_t id = (size_t)row * LOOK + c;
        const float yv = y[id];
        if (combine) {
          float yn = yv + hb1 * K0[id] + hb2 * K1[id] + hb3 * K2[id] +
                     hb4 * K3[id] + hb5 * K4[id] + hb6 * kv;
          y[id] = yn;
          zv = yn;
        } else {
          kout[id] = kv;
          zv = yv + pc * kv;
          if (p1 != 0.f) zv += p1 * K0[id];
          if (p2 != 0.f) zv += p2 * K1[id];
          if (p3 != 0.f) zv += p3 * K2[id];
          if (p4 != 0.f) zv += p4 * K3[id];
          if (p5 != 0.f) zv += p5 * K4[id];
        }
      }
      unsigned short hi = f2bf(zv);
      unsigned short lo = f2bf(zv - bf2f(hi));
      zs[0][rloc][c] = (short)hi;
      zs[1][rloc][c] = (short)lo;
    }
  }
  __syncthreads();

  // ---- Part 2: H1(next) = leaky(z @ W1next + b1next)
  bf16x8 zfh[2], zfl[2];
#pragma unroll
  for (int mi = 0; mi < 2; ++mi) {
    zfh[mi] = *(const bf16x8*)&zs[0][mi * 16 + r15][kc * 8];
    zfl[mi] = *(const bf16x8*)&zs[1][mi * 16 + r15][kc * 8];
  }
  const int crow = kc * 4;
#pragma unroll
  for (int nj = 0; nj < 16; ++nj) {
    const int col = wave * 256 + nj * 16 + r15;
    const size_t bo = (size_t)col * 32 + kc * 8;
    bf16x8 bh = *(const bf16x8*)&W1Tnh[bo];
    bf16x8 bl = *(const bf16x8*)&W1Tnl[bo];
    f32x4 a0 = (f32x4){0.f, 0.f, 0.f, 0.f};
    f32x4 a1 = (f32x4){0.f, 0.f, 0.f, 0.f};
    a0 = __builtin_amdgcn_mfma_f32_16x16x32_bf16(zfh[0], bh, a0, 0, 0, 0);
    a0 = __builtin_amdgcn_mfma_f32_16x16x32_bf16(zfh[0], bl, a0, 0, 0, 0);
    a0 = __builtin_amdgcn_mfma_f32_16x16x32_bf16(zfl[0], bh, a0, 0, 0, 0);
    a1 = __builtin_amdgcn_mfma_f32_16x16x32_bf16(zfh[1], bh, a1, 0, 0, 0);
    a1 = __builtin_amdgcn_mfma_f32_16x16x32_bf16(zfh[1], bl, a1, 0, 0, 0);
    a1 = __builtin_amdgcn_mfma_f32_16x16x32_bf16(zfl[1], bh, a1, 0, 0, 0);
    const float bias = b1n[col];
#pragma unroll
    for (int mi = 0; mi < 2; ++mi) {
      const f32x4 av = mi ? a1 : a0;
      const int rbase = row0 + mi * 16 + crow;
#pragma unroll
      for (int r = 0; r < 4; ++r) {
        float v = leaky(av[r] + bias);
        unsigned short hi = f2bf(v);
        unsigned short lo = f2bf(v - bf2f(hi));
        const size_t o = (size_t)(rbase + r) * HID + col;
        H1h[o] = (short)hi;
        H1l[o] = (short)lo;
      }
    }
  }
}

// ---------------------------------------------------------------------------
__global__ __launch_bounds__(256) void k_readout(const float* __restrict__ y,
                                                 const float* __restrict__ Wf,
                                                 const float* __restrict__ bf,
                                                 float* __restrict__ out) {
  const int r = blockIdx.x * blockDim.x + threadIdx.x;
  if (r >= BATCH) return;
  float acc = bf[0];
#pragma unroll
  for (int c = 0; c < LOOK; ++c) acc += y[(size_t)r * LOOK + c] * Wf[c];
  out[r] = acc;
}

// ---------------------------------------------------------------------------
extern "C" void kernel_launch(void* const* d_in, const int* in_sizes, int n_in,
                              void* d_out, int out_size, void* d_ws,
                              size_t ws_size, hipStream_t stream) {
  const float* y0 = (const float*)d_in[0];
  const float* W1 = (const float*)d_in[1];
  const float* b1 = (const float*)d_in[2];
  const float* W2 = (const float*)d_in[3];
  const float* b2 = (const float*)d_in[4];
  const float* W3 = (const float*)d_in[5];
  const float* b3 = (const float*)d_in[6];
  const float* Wf = (const float*)d_in[7];
  const float* bf = (const float*)d_in[8];
  float* out = (float*)d_out;

  const size_t NY = (size_t)BATCH * LOOK;
  float* f = (float*)d_ws;
  float* y = f;
  float* kk[5];
  for (int i = 0; i < 5; ++i) kk[i] = f + NY * (1 + i);
  char* p = (char*)(f + NY * 6);
  short* zh = (short*)p; p += (size_t)BATCH * 32 * 2;
  short* zl = (short*)p; p += (size_t)BATCH * 32 * 2;
  short* H1h = (short*)p; p += (size_t)BATCH * HID * 2;
  short* H1l = (short*)p; p += (size_t)BATCH * HID * 2;
  float* kpart = (float*)p; p += (size_t)8 * BATCH * 32 * 4;
  short* W2Th = (short*)p; p += (size_t)HID * HID * 2;
  short* W2Tl = (short*)p; p += (size_t)HID * HID * 2;
  short* W1Th = (short*)p; p += (size_t)DEPTH * HID * 32 * 2;
  short* W1Tl = (short*)p; p += (size_t)DEPTH * HID * 32 * 2;
  short* W3Th = (short*)p; p += (size_t)32 * HID * 2;
  short* W3Tl = (short*)p;

  hipMemcpyAsync(y, y0, NY * sizeof(float), hipMemcpyDeviceToDevice, stream);

  k_w1t_all<<<dim3(DEPTH * 1024 * 32 / 256), 256, 0, stream>>>(W1, W1Th, W1Tl);
  k_zinit<<<dim3(BATCH * 32 / 256), 256, 0, stream>>>(y0, zh, zl);
  k_l1<<<dim3(BATCH / 128, HID / 256), 512, 0, stream>>>(zh, zl, W1Th, W1Tl,
                                                         b1, H1h, H1l);

  const double hh = 1.0 / 16.0;
  static const double A[6][5] = {
      {0, 0, 0, 0, 0},
      {1.0 / 5, 0, 0, 0, 0},
      {3.0 / 40, 9.0 / 40, 0, 0, 0},
      {44.0 / 45, -56.0 / 15, 32.0 / 9, 0, 0},
      {19372.0 / 6561, -25360.0 / 2187, 64448.0 / 6561, -212.0 / 729, 0},
      {9017.0 / 3168, -355.0 / 33, 46732.0 / 5247, 49.0 / 176,
       -5103.0 / 18656},
  };
  static const double Bb[6] = {35.0 / 384,  0,              500.0 / 1113,
                               125.0 / 192, -2187.0 / 6784, 11.0 / 84};

  const float hb1 = (float)(hh * Bb[0]);
  const float hb2 = (float)(hh * Bb[1]);
  const float hb3 = (float)(hh * Bb[2]);
  const float hb4 = (float)(hh * Bb[3]);
  const float hb5 = (float)(hh * Bb[4]);
  const float hb6 = (float)(hh * Bb[5]);

  for (int d = 0; d < DEPTH; ++d) {
    const float* W2d = W2 + (size_t)d * HID * HID;
    const float* b2d = b2 + (size_t)d * HID;
    const float* W3d = W3 + (size_t)d * HID * LOOK;
    const float* b3d = b3 + (size_t)d * LOOK;

    k_w2split<<<dim3(16, 16), 256, 0, stream>>>(W2d, W2Th, W2Tl);
    k_w3t<<<dim3(128), 256, 0, stream>>>(W3d, W3Th, W3Tl);

    for (int s = 0; s < NSTEPS; ++s) {
      for (int st = 0; st < 6; ++st) {
        float pv[5] = {0.f, 0.f, 0.f, 0.f, 0.f};
        float pc = 0.f;
        if (st < 5) {
          for (int jj = 0; jj < 5; ++jj)
            if (jj < st) pv[jj] = (float)(hh * A[st + 1][jj]);
          pc = (float)(hh * A[st + 1][st]);
        }
        int dn = d;
        if (st == 5 && s == NSTEPS - 1) dn = (d + 1 < DEPTH) ? d + 1 : d;
        const short* W1Tnh = W1Th + (size_t)dn * HID * 32;
        const short* W1Tnl = W1Tl + (size_t)dn * HID * 32;
        const float* b1n = b1 + (size_t)dn * HID;

        k_mid<<<dim3(1024), 256, 0, stream>>>(H1h, H1l, W2Th, W2Tl, b2d,
                                              W3Th, W3Tl, kpart);
        const int comb = (st == 5) ? 1 : 0;
        float* kout = (st < 5) ? kk[st] : kk[0];
        k_l3l1<<<dim3(BATCH / 32), 256, 0, stream>>>(
            kpart, b3d, kout, kk[0], kk[1], kk[2], kk[3], kk[4], y, comb,
            pv[0], pv[1], pv[2], pv[3], pv[4], pc, hb1, hb2, hb3, hb4, hb5,
            hb6, W1Tnh, W1Tnl, b1n, H1h, H1l);
      }
    }
  }

  k_readout<<<dim3(BATCH / 256), 256, 0, stream>>>(y, Wf, bf, out);
}

// Round 13
// 114433.984 us; speedup vs baseline: 1.4294x; 1.0031x over previous
//
#include <hip/hip_runtime.h>

#define BATCH 16384
#define LOOK 30
#define HID 1024
#define DEPTH 10
#define NSTEPS 16
#define ALPHA 0.3f

typedef short bf16x8 __attribute__((ext_vector_type(8)));
typedef float f32x4 __attribute__((ext_vector_type(4)));

__device__ __forceinline__ float leaky(float x) { return x > 0.f ? x : ALPHA * x; }

__device__ __forceinline__ unsigned short f2bf(float x) {
  unsigned u = __builtin_bit_cast(unsigned, x);
  unsigned r = u + 0x7FFFu + ((u >> 16) & 1u);
  return (unsigned short)(r >> 16);
}
__device__ __forceinline__ float bf2f(unsigned short b) {
  return __builtin_bit_cast(float, (unsigned)b << 16);
}

#define GLD_LDS16(g, l)                                        \
  __builtin_amdgcn_global_load_lds(                            \
      (const __attribute__((address_space(1))) void*)(g),      \
      (__attribute__((address_space(3))) void*)(l), 16, 0, 0)

// ---------------------------------------------------------------------------
// Prep: W2[k][n] -> W2T[n][k] hi/lo bf16. grid (16,16), 256 thr.
// ---------------------------------------------------------------------------
__global__ __launch_bounds__(256) void k_w2split(const float* __restrict__ W2d,
                                                 short* __restrict__ W2Th,
                                                 short* __restrict__ W2Tl) {
  __shared__ float t[64][65];
  const int kb = blockIdx.x * 64;
  const int nb = blockIdx.y * 64;
  for (int i = threadIdx.x; i < 4096; i += 256) {
    int r = i >> 6, c = i & 63;
    t[r][c] = W2d[(size_t)(kb + r) * HID + nb + c];
  }
  __syncthreads();
  for (int i = threadIdx.x; i < 4096; i += 256) {
    int r = i >> 6, c = i & 63;
    float v = t[c][r];
    unsigned short hi = f2bf(v);
    unsigned short lo = f2bf(v - bf2f(hi));
    W2Th[(size_t)(nb + r) * HID + kb + c] = (short)hi;
    W2Tl[(size_t)(nb + r) * HID + kb + c] = (short)lo;
  }
}

// Prep (ALL depths): W1[d][30][1024] -> W1T[d][1024 n][32 k] hi/lo. grid 1280.
__global__ __launch_bounds__(256) void k_w1t_all(const float* __restrict__ W1,
                                                 short* __restrict__ W1Th,
                                                 short* __restrict__ W1Tl) {
  const int idx = blockIdx.x * 256 + threadIdx.x;
  if (idx >= DEPTH * 1024 * 32) return;
  const int d = idx >> 15;
  const int rem = idx & 32767;
  const int n = rem >> 5, k = rem & 31;
  float v = (k < LOOK) ? W1[(size_t)d * LOOK * HID + (size_t)k * HID + n] : 0.f;
  unsigned short hi = f2bf(v);
  unsigned short lo = f2bf(v - bf2f(hi));
  W1Th[idx] = (short)hi;
  W1Tl[idx] = (short)lo;
}

// Prep: W3[1024][30] -> W3T[32 n][1024 k] hi/lo (n 30,31 zero). grid 128.
__global__ __launch_bounds__(256) void k_w3t(const float* __restrict__ W3d,
                                             short* __restrict__ W3Th,
                                             short* __restrict__ W3Tl) {
  const int idx = blockIdx.x * 256 + threadIdx.x;
  if (idx >= 32 * 1024) return;
  const int n = idx >> 10, k = idx & 1023;
  float v = (n < LOOK) ? W3d[(size_t)k * LOOK + n] : 0.f;
  unsigned short hi = f2bf(v);
  unsigned short lo = f2bf(v - bf2f(hi));
  W3Th[idx] = (short)hi;
  W3Tl[idx] = (short)lo;
}

// Init: z = y0 (padded to 32 cols) hi/lo. grid 2048.
__global__ __launch_bounds__(256) void k_zinit(const float* __restrict__ y0,
                                               short* __restrict__ zh,
                                               short* __restrict__ zl) {
  const int idx = blockIdx.x * 256 + threadIdx.x;
  if (idx >= BATCH * 32) return;
  const int r = idx >> 5, c = idx & 31;
  float v = (c < LOOK) ? y0[(size_t)r * LOOK + c] : 0.f;
  unsigned short hi = f2bf(v);
  unsigned short lo = f2bf(v - bf2f(hi));
  zh[idx] = (short)hi;
  zl[idx] = (short)lo;
}

// ---------------------------------------------------------------------------
// Layer1 standalone (first eval only): H1 = leaky(z @ W1 + b1). [R4 verbatim]
// ---------------------------------------------------------------------------
__global__ __launch_bounds__(512, 2) void k_l1(
    const short* __restrict__ zh, const short* __restrict__ zl,
    const short* __restrict__ W1Th, const short* __restrict__ W1Tl,
    const float* __restrict__ b1d, short* __restrict__ H1h,
    short* __restrict__ H1l) {
  __shared__ short za[2][128 * 32];
  const int tid = threadIdx.x, lane = tid & 63, wave = tid >> 6;
  const int row0 = blockIdx.x * 128;
  const int n0 = blockIdx.y * 256;
  const int wm = wave >> 2, wn = wave & 3;
  const int r15 = lane & 15;
  const int bk = (lane >> 4) * 8;

  bf16x8 bh[4], bl[4];
#pragma unroll
  for (int nj = 0; nj < 4; ++nj) {
    const size_t bo = (size_t)(n0 + wn * 64 + nj * 16 + r15) * 32 + bk;
    bh[nj] = *(const bf16x8*)&W1Th[bo];
    bl[nj] = *(const bf16x8*)&W1Tl[bo];
  }

  GLD_LDS16((const char*)(zh + (size_t)row0 * 32) + tid * 16, &za[0][tid * 8]);
  GLD_LDS16((const char*)(zl + (size_t)row0 * 32) + tid * 16, &za[1][tid * 8]);
  __syncthreads();

  bf16x8 ah[4], al[4];
#pragma unroll
  for (int mi = 0; mi < 4; ++mi) {
    const int ao = (wm * 64 + mi * 16 + r15) * 32 + bk;
    ah[mi] = *(const bf16x8*)&za[0][ao];
    al[mi] = *(const bf16x8*)&za[1][ao];
  }

  f32x4 acc[4][4];
#pragma unroll
  for (int i = 0; i < 4; ++i)
#pragma unroll
    for (int j = 0; j < 4; ++j) acc[i][j] = (f32x4){0.f, 0.f, 0.f, 0.f};

#pragma unroll
  for (int mi = 0; mi < 4; ++mi)
#pragma unroll
    for (int nj = 0; nj < 4; ++nj)
      acc[mi][nj] = __builtin_amdgcn_mfma_f32_16x16x32_bf16(ah[mi], bh[nj],
                                                            acc[mi][nj], 0, 0, 0);
#pragma unroll
  for (int mi = 0; mi < 4; ++mi)
#pragma unroll
    for (int nj = 0; nj < 4; ++nj)
      acc[mi][nj] = __builtin_amdgcn_mfma_f32_16x16x32_bf16(ah[mi], bl[nj],
                                                            acc[mi][nj], 0, 0, 0);
#pragma unroll
  for (int mi = 0; mi < 4; ++mi)
#pragma unroll
    for (int nj = 0; nj < 4; ++nj)
      acc[mi][nj] = __builtin_amdgcn_mfma_f32_16x16x32_bf16(al[mi], bh[nj],
                                                            acc[mi][nj], 0, 0, 0);

  const int crow = (lane >> 4) * 4;
#pragma unroll
  for (int nj = 0; nj < 4; ++nj) {
    const int col = n0 + wn * 64 + nj * 16 + r15;
    const float bias = b1d[col];
#pragma unroll
    for (int mi = 0; mi < 4; ++mi) {
      const int rb = row0 + wm * 64 + mi * 16 + crow;
#pragma unroll
      for (int r = 0; r < 4; ++r) {
        float v = leaky(acc[mi][nj][r] + bias);
        unsigned short hi = f2bf(v);
        unsigned short lo = f2bf(v - bf2f(hi));
        const size_t o = (size_t)(rb + r) * HID + col;
        H1h[o] = (short)hi;
        H1l[o] = (short)lo;
      }
    }
  }
}

// ---------------------------------------------------------------------------
// Mid (MFMA): 128x128 tile, BK=32, 4 waves, 64KB LDS, 2 blocks/CU.
// [R12 structure]  NEW: product-major MFMA order (same-acc dep distance 16)
// in both the main loop and the kpart epilogue GEMM. Arithmetic identical.
// grid 1024 blocks (128 mb x 8 nb), XCD-chunked swizzle.
// ---------------------------------------------------------------------------
__global__ __launch_bounds__(256, 2) void k_mid(
    const short* __restrict__ H1h, const short* __restrict__ H1l,
    const short* __restrict__ W2Th, const short* __restrict__ W2Tl,
    const float* __restrict__ b2d, const short* __restrict__ W3Th,
    const short* __restrict__ W3Tl, float* __restrict__ kpart) {
  __shared__ char lds[65536];

  const int tid = threadIdx.x;
  const int lane = tid & 63;
  const int wave = tid >> 6;  // 0..3

  const int bid = blockIdx.x;
  const int wg = (bid & 7) * 128 + (bid >> 3);
  const int mb = wg >> 3, nb = wg & 7;
  const int row0 = mb * 128;
  const int n0 = nb * 128;
  const int wm = wave >> 1;
  const int wnb = wave & 1;
  const int r15 = lane & 15;
  const int kq = lane >> 4;
  const int l7 = lane & 7;
  const int l3 = lane >> 3;

  const char* srcB[8];
  {
    const int s = l7 ^ l3;
    const char* hsrc;
    const char* lsrc;
    int rbase;
    if (wave < 2) {
      hsrc = (const char*)H1h;
      lsrc = (const char*)H1l;
      rbase = row0;
    } else {
      hsrc = (const char*)W2Th;
      lsrc = (const char*)W2Tl;
      rbase = n0;
    }
    const char* base = (s < 4) ? hsrc : lsrc;
    const int w2 = wave & 1;
#pragma unroll
    for (int i = 0; i < 8; ++i) {
      const int c = w2 * 8 + i;
      const int rloc = c * 8 + l3;
      srcB[i] = base + (size_t)(rbase + rloc) * 2048 + (size_t)(s & 3) * 16;
    }
  }
  const int dchunk0 = (wave < 2) ? (wave & 1) * 8192 : 16384 + (wave & 1) * 8192;

  const int offA0 = (wm * 64 + r15) * 128 + ((0 + kq) ^ l7) * 16;
  const int offA1 = (wm * 64 + r15) * 128 + ((4 + kq) ^ l7) * 16;
  const int offB0 = 16384 + (wnb * 64 + r15) * 128 + ((0 + kq) ^ l7) * 16;
  const int offB1 = 16384 + (wnb * 64 + r15) * 128 + ((4 + kq) ^ l7) * 16;

  f32x4 acc[4][4];
#pragma unroll
  for (int i = 0; i < 4; ++i)
#pragma unroll
    for (int j = 0; j < 4; ++j) acc[i][j] = (f32x4){0.f, 0.f, 0.f, 0.f};

#define STAGE(buf, kb)                                                   \
  {                                                                      \
    _Pragma("unroll") for (int i = 0; i < 8; ++i) {                      \
      GLD_LDS16(srcB[i] + (kb), &lds[(buf)*32768 + dchunk0 + i * 1024]); \
    }                                                                    \
  }

  STAGE(0, 0);
  __syncthreads();

  int cur = 0;
  for (int t = 0; t < 32; ++t) {
    if (t < 31) STAGE(cur ^ 1, (t + 1) * 64);

    const char* buf = &lds[cur * 32768];
    bf16x8 bh[4], bl[4], ah[4], al[4];
#pragma unroll
    for (int nj = 0; nj < 4; ++nj) {
      bh[nj] = *(const bf16x8*)(buf + offB0 + nj * 2048);
      bl[nj] = *(const bf16x8*)(buf + offB1 + nj * 2048);
    }
#pragma unroll
    for (int mi = 0; mi < 4; ++mi) {
      ah[mi] = *(const bf16x8*)(buf + offA0 + mi * 2048);
      al[mi] = *(const bf16x8*)(buf + offA1 + mi * 2048);
    }
    // product-major: same-acc dependency distance = 16 instructions
#pragma unroll
    for (int mi = 0; mi < 4; ++mi)
#pragma unroll
      for (int nj = 0; nj < 4; ++nj)
        acc[mi][nj] = __builtin_amdgcn_mfma_f32_16x16x32_bf16(
            ah[mi], bh[nj], acc[mi][nj], 0, 0, 0);
#pragma unroll
    for (int mi = 0; mi < 4; ++mi)
#pragma unroll
      for (int nj = 0; nj < 4; ++nj)
        acc[mi][nj] = __builtin_amdgcn_mfma_f32_16x16x32_bf16(
            ah[mi], bl[nj], acc[mi][nj], 0, 0, 0);
#pragma unroll
    for (int mi = 0; mi < 4; ++mi)
#pragma unroll
      for (int nj = 0; nj < 4; ++nj)
        acc[mi][nj] = __builtin_amdgcn_mfma_f32_16x16x32_bf16(
            al[mi], bh[nj], acc[mi][nj], 0, 0, 0);
    __syncthreads();
    cur ^= 1;
  }
#undef STAGE

  // ===== epilogue: kpart[nb] partial of kout via on-chip transpose =====
#pragma unroll
  for (int nj = 0; nj < 4; ++nj) {
    const int k = wnb * 64 + nj * 16 + r15;
    const float bv = b2d[n0 + k];
    const int ksub = k >> 4;
    const int klo = (k & 15) * 2;
#pragma unroll
    for (int mi = 0; mi < 4; ++mi) {
      const int rowq = wm * 16 + mi * 4 + kq;
      const int xr = kq & 3;
      const int base = (rowq * 8 + ksub) * 128 + klo;
#pragma unroll
      for (int r = 0; r < 4; ++r) {
        float v = leaky(acc[mi][nj][r] + bv);
        unsigned short hi = f2bf(v);
        unsigned short lo = f2bf(v - bf2f(hi));
        const int off = base + ((r ^ xr) & 3) * 32;
        *(short*)(lds + off) = (short)hi;
        *(short*)(lds + 32768 + off) = (short)lo;
      }
    }
  }
  __syncthreads();

  // small GEMM: rows (wave*32..+31) x N=32 x K=128, product-major order
  {
    const int kq8 = kq * 8;
    f32x4 kacc[2][2];
#pragma unroll
    for (int i = 0; i < 2; ++i)
#pragma unroll
      for (int j = 0; j < 2; ++j) kacc[i][j] = (f32x4){0.f, 0.f, 0.f, 0.f};

#pragma unroll
    for (int kt = 0; kt < 4; ++kt) {
      bf16x8 ah2[2], al2[2], wh[2], wl[2];
#pragma unroll
      for (int mii = 0; mii < 2; ++mii) {
        const int row = wave * 32 + mii * 16 + r15;
        const int rowq = row >> 2;
        const int kk = kt * 32 + kq8;
        const int byteA = (rowq * 8 + (kk >> 4)) * 128 +
                          (((row & 3) ^ (rowq & 3)) & 3) * 32 + (kk & 15) * 2;
        ah2[mii] = *(const bf16x8*)(lds + byteA);
        al2[mii] = *(const bf16x8*)(lds + 32768 + byteA);
      }
#pragma unroll
      for (int njj = 0; njj < 2; ++njj) {
        const int col = njj * 16 + r15;
        const size_t wo = (size_t)col * 1024 + n0 + kt * 32 + kq8;
        wh[njj] = *(const bf16x8*)&W3Th[wo];
        wl[njj] = *(const bf16x8*)&W3Tl[wo];
      }
      // product-major: same-acc distance 4
#pragma unroll
      for (int mii = 0; mii < 2; ++mii)
#pragma unroll
        for (int njj = 0; njj < 2; ++njj)
          kacc[mii][njj] = __builtin_amdgcn_mfma_f32_16x16x32_bf16(
              ah2[mii], wh[njj], kacc[mii][njj], 0, 0, 0);
#pragma unroll
      for (int mii = 0; mii < 2; ++mii)
#pragma unroll
        for (int njj = 0; njj < 2; ++njj)
          kacc[mii][njj] = __builtin_amdgcn_mfma_f32_16x16x32_bf16(
              ah2[mii], wl[njj], kacc[mii][njj], 0, 0, 0);
#pragma unroll
      for (int mii = 0; mii < 2; ++mii)
#pragma unroll
        for (int njj = 0; njj < 2; ++njj)
          kacc[mii][njj] = __builtin_amdgcn_mfma_f32_16x16x32_bf16(
              al2[mii], wh[njj], kacc[mii][njj], 0, 0, 0);
    }

    const int crow2 = kq * 4;
#pragma unroll
    for (int njj = 0; njj < 2; ++njj) {
      const int col = njj * 16 + r15;
#pragma unroll
      for (int mii = 0; mii < 2; ++mii) {
        const int rbase = row0 + wave * 32 + mii * 16 + crow2;
#pragma unroll
        for (int r = 0; r < 4; ++r) {
          kpart[(size_t)nb * ((size_t)BATCH * 32) + (size_t)(rbase + r) * 32 +
                col] = kacc[mii][njj][r];
        }
      }
    }
  }
}

// ---------------------------------------------------------------------------
// Fused combine + next-stage Layer1, per 32-row slice. grid 512, 256 thr.
// Part 1: kv = b3 + sum_nb kpart; DoPri combine; z -> LDS. [R12 verbatim]
// Part 2: H1(next) = leaky(z @ W1next + b1next), a0/a1 interleaved MFMA.
// ---------------------------------------------------------------------------
__global__ __launch_bounds__(256, 4) void k_l3l1(
    const float* __restrict__ kpart, const float* __restrict__ b3d,
    float* __restrict__ kout, const float* __restrict__ K0,
    const float* __restrict__ K1, const float* __restrict__ K2,
    const float* __restrict__ K3, const float* __restrict__ K4,
    float* __restrict__ y, int combine, float p1, float p2, float p3,
    float p4, float p5, float pc, float hb1, float hb2, float hb3, float hb4,
    float hb5, float hb6, const short* __restrict__ W1Tnh,
    const short* __restrict__ W1Tnl, const float* __restrict__ b1n,
    short* __restrict__ H1h, short* __restrict__ H1l) {
  __shared__ short zs[2][32][40];

  const int tid = threadIdx.x, lane = tid & 63, wave = tid >> 6;
  const int row0 = blockIdx.x * 32;
  const int wm = wave & 1, wn = wave >> 1;
  const int r15 = lane & 15;
  const int kc = lane >> 4;

  {
    const int c = wn * 16 + r15;
    const int rb = wm * 16 + kc * 4;
    const float bias = (c < LOOK) ? b3d[c] : 0.f;
#pragma unroll
    for (int r = 0; r < 4; ++r) {
      const int rloc = rb + r;
      const int row = row0 + rloc;
      float zv = 0.f;
      if (c < LOOK) {
        float kv = bias;
#pragma unroll
        for (int nbi = 0; nbi < 8; ++nbi)
          kv += kpart[(size_t)nbi * ((size_t)BATCH * 32) + (size_t)row * 32 + c];
        const size_t id = (size_t)row * LOOK + c;
        const float yv = y[id];
        if (combine) {
          float yn = yv + hb1 * K0[id] + hb2 * K1[id] + hb3 * K2[id] +
                     hb4 * K3[id] + hb5 * K4[id] + hb6 * kv;
          y[id] = yn;
          zv = yn;
        } else {
          kout[id] = kv;
          zv = yv + pc * kv;
          if (p1 != 0.f) zv += p1 * K0[id];
          if (p2 != 0.f) zv += p2 * K1[id];
          if (p3 != 0.f) zv += p3 * K2[id];
          if (p4 != 0.f) zv += p4 * K3[id];
          if (p5 != 0.f) zv += p5 * K4[id];
        }
      }
      unsigned short hi = f2bf(zv);
      unsigned short lo = f2bf(zv - bf2f(hi));
      zs[0][rloc][c] = (short)hi;
      zs[1][rloc][c] = (short)lo;
    }
  }
  __syncthreads();

  bf16x8 zfh[2], zfl[2];
#pragma unroll
  for (int mi = 0; mi < 2; ++mi) {
    zfh[mi] = *(const bf16x8*)&zs[0][mi * 16 + r15][kc * 8];
    zfl[mi] = *(const bf16x8*)&zs[1][mi * 16 + r15][kc * 8];
  }
  const int crow = kc * 4;
#pragma unroll
  for (int nj = 0; nj < 16; ++nj) {
    const int col = wave * 256 + nj * 16 + r15;
    const size_t bo = (size_t)col * 32 + kc * 8;
    bf16x8 bh = *(const bf16x8*)&W1Tnh[bo];
    bf16x8 bl = *(const bf16x8*)&W1Tnl[bo];
    f32x4 a0 = (f32x4){0.f, 0.f, 0.f, 0.f};
    f32x4 a1 = (f32x4){0.f, 0.f, 0.f, 0.f};
    // interleaved a0/a1: same-acc distance 2 (and nj iterations independent)
    a0 = __builtin_amdgcn_mfma_f32_16x16x32_bf16(zfh[0], bh, a0, 0, 0, 0);
    a1 = __builtin_amdgcn_mfma_f32_16x16x32_bf16(zfh[1], bh, a1, 0, 0, 0);
    a0 = __builtin_amdgcn_mfma_f32_16x16x32_bf16(zfh[0], bl, a0, 0, 0, 0);
    a1 = __builtin_amdgcn_mfma_f32_16x16x32_bf16(zfh[1], bl, a1, 0, 0, 0);
    a0 = __builtin_amdgcn_mfma_f32_16x16x32_bf16(zfl[0], bh, a0, 0, 0, 0);
    a1 = __builtin_amdgcn_mfma_f32_16x16x32_bf16(zfl[1], bh, a1, 0, 0, 0);
    const float bias = b1n[col];
#pragma unroll
    for (int mi = 0; mi < 2; ++mi) {
      const f32x4 av = mi ? a1 : a0;
      const int rbase = row0 + mi * 16 + crow;
#pragma unroll
      for (int r = 0; r < 4; ++r) {
        float v = leaky(av[r] + bias);
        unsigned short hi = f2bf(v);
        unsigned short lo = f2bf(v - bf2f(hi));
        const size_t o = (size_t)(rbase + r) * HID + col;
        H1h[o] = (short)hi;
        H1l[o] = (short)lo;
      }
    }
  }
}

// ---------------------------------------------------------------------------
__global__ __launch_bounds__(256) void k_readout(const float* __restrict__ y,
                                                 const float* __restrict__ Wf,
                                                 const float* __restrict__ bf,
                                                 float* __restrict__ out) {
  const int r = blockIdx.x * blockDim.x + threadIdx.x;
  if (r >= BATCH) return;
  float acc = bf[0];
#pragma unroll
  for (int c = 0; c < LOOK; ++c) acc += y[(size_t)r * LOOK + c] * Wf[c];
  out[r] = acc;
}

// ---------------------------------------------------------------------------
extern "C" void kernel_launch(void* const* d_in, const int* in_sizes, int n_in,
                              void* d_out, int out_size, void* d_ws,
                              size_t ws_size, hipStream_t stream) {
  const float* y0 = (const float*)d_in[0];
  const float* W1 = (const float*)d_in[1];
  const float* b1 = (const float*)d_in[2];
  const float* W2 = (const float*)d_in[3];
  const float* b2 = (const float*)d_in[4];
  const float* W3 = (const float*)d_in[5];
  const float* b3 = (const float*)d_in[6];
  const float* Wf = (const float*)d_in[7];
  const float* bf = (const float*)d_in[8];
  float* out = (float*)d_out;

  const size_t NY = (size_t)BATCH * LOOK;
  float* f = (float*)d_ws;
  float* y = f;
  float* kk[5];
  for (int i = 0; i < 5; ++i) kk[i] = f + NY * (1 + i);
  char* p = (char*)(f + NY * 6);
  short* zh = (short*)p; p += (size_t)BATCH * 32 * 2;
  short* zl = (short*)p; p += (size_t)BATCH * 32 * 2;
  short* H1h = (short*)p; p += (size_t)BATCH * HID * 2;
  short* H1l = (short*)p; p += (size_t)BATCH * HID * 2;
  float* kpart = (float*)p; p += (size_t)8 * BATCH * 32 * 4;
  short* W2Th = (short*)p; p += (size_t)HID * HID * 2;
  short* W2Tl = (short*)p; p += (size_t)HID * HID * 2;
  short* W1Th = (short*)p; p += (size_t)DEPTH * HID * 32 * 2;
  short* W1Tl = (short*)p; p += (size_t)DEPTH * HID * 32 * 2;
  short* W3Th = (short*)p; p += (size_t)32 * HID * 2;
  short* W3Tl = (short*)p;

  hipMemcpyAsync(y, y0, NY * sizeof(float), hipMemcpyDeviceToDevice, stream);

  k_w1t_all<<<dim3(DEPTH * 1024 * 32 / 256), 256, 0, stream>>>(W1, W1Th, W1Tl);
  k_zinit<<<dim3(BATCH * 32 / 256), 256, 0, stream>>>(y0, zh, zl);
  k_l1<<<dim3(BATCH / 128, HID / 256), 512, 0, stream>>>(zh, zl, W1Th, W1Tl,
                                                         b1, H1h, H1l);

  const double hh = 1.0 / 16.0;
  static const double A[6][5] = {
      {0, 0, 0, 0, 0},
      {1.0 / 5, 0, 0, 0, 0},
      {3.0 / 40, 9.0 / 40, 0, 0, 0},
      {44.0 / 45, -56.0 / 15, 32.0 / 9, 0, 0},
      {19372.0 / 6561, -25360.0 / 2187, 64448.0 / 6561, -212.0 / 729, 0},
      {9017.0 / 3168, -355.0 / 33, 46732.0 / 5247, 49.0 / 176,
       -5103.0 / 18656},
  };
  static const double Bb[6] = {35.0 / 384,  0,              500.0 / 1113,
                               125.0 / 192, -2187.0 / 6784, 11.0 / 84};

  const float hb1 = (float)(hh * Bb[0]);
  const float hb2 = (float)(hh * Bb[1]);
  const float hb3 = (float)(hh * Bb[2]);
  const float hb4 = (float)(hh * Bb[3]);
  const float hb5 = (float)(hh * Bb[4]);
  const float hb6 = (float)(hh * Bb[5]);

  for (int d = 0; d < DEPTH; ++d) {
    const float* W2d = W2 + (size_t)d * HID * HID;
    const float* b2d = b2 + (size_t)d * HID;
    const float* W3d = W3 + (size_t)d * HID * LOOK;
    const float* b3d = b3 + (size_t)d * LOOK;

    k_w2split<<<dim3(16, 16), 256, 0, stream>>>(W2d, W2Th, W2Tl);
    k_w3t<<<dim3(128), 256, 0, stream>>>(W3d, W3Th, W3Tl);

    for (int s = 0; s < NSTEPS; ++s) {
      for (int st = 0; st < 6; ++st) {
        float pv[5] = {0.f, 0.f, 0.f, 0.f, 0.f};
        float pc = 0.f;
        if (st < 5) {
          for (int jj = 0; jj < 5; ++jj)
            if (jj < st) pv[jj] = (float)(hh * A[st + 1][jj]);
          pc = (float)(hh * A[st + 1][st]);
        }
        int dn = d;
        if (st == 5 && s == NSTEPS - 1) dn = (d + 1 < DEPTH) ? d + 1 : d;
        const short* W1Tnh = W1Th + (size_t)dn * HID * 32;
        const short* W1Tnl = W1Tl + (size_t)dn * HID * 32;
        const float* b1n = b1 + (size_t)dn * HID;

        k_mid<<<dim3(1024), 256, 0, stream>>>(H1h, H1l, W2Th, W2Tl, b2d,
                                              W3Th, W3Tl, kpart);
        const int comb = (st == 5) ? 1 : 0;
        float* kout = (st < 5) ? kk[st] : kk[0];
        k_l3l1<<<dim3(BATCH / 32), 256, 0, stream>>>(
            kpart, b3d, kout, kk[0], kk[1], kk[2], kk[3], kk[4], y, comb,
            pv[0], pv[1], pv[2], pv[3], pv[4], pc, hb1, hb2, hb3, hb4, hb5,
            hb6, W1Tnh, W1Tnl, b1n, H1h, H1l);
      }
    }
  }

  k_readout<<<dim3(BATCH / 256), 256, 0, stream>>>(y, Wf, bf, out);
}